// Round 3
// baseline (170.277 us; speedup 1.0000x reference)
//
#include <hip/hip_runtime.h>
#include <cmath>

// Problem constants
#define BATCH 64
#define SEQLEN 512
#define NFEAT 64
#define NPATCH 125
#define PATCHLEN 16
#define STRIDE_ 4
#define PREDLEN 96
#define NCOLS 500    // NPATCH * 4 qubits
#define MG 4         // m's per block
#define NMG (NFEAT / MG)  // 16
#define TPAD 521     // xt row pad (odd -> <=2-way bank aliasing on sim reads)
#define EPAD 508     // enc row pad (16B-aligned, bank-spread across m lanes)

// One block per (b, m-group of 4). 1024 blocks x 256 threads.
// __launch_bounds__(256,4): cap VGPR at 128 -> 4 waves/SIMD (16 waves/CU with
// 4 blocks/CU; grid/CU = exactly 4).
//  phase 0: threads 0..7 build Rot gate matrices; all threads stage
//           x[b, :, m0:m0+4] (one float4 per row) into LDS transposed xt[m][t]
//  phase 1: 500 sims (4 m x 125 patches), ~2 per thread, state in regs
//  phase 2: head GEMM out[b, 0:96, m0:m0+4]; thread (m, o) strides o by 64
__global__ __launch_bounds__(256, 4) void qml_fused_kernel(
    const float* __restrict__ x,     // [B, L, M]
    const float* __restrict__ w,     // [2, 4, 3]
    const float* __restrict__ hw,    // [PRED, NCOLS]
    const float* __restrict__ hb,    // [PRED]
    float* __restrict__ out)         // [B, PRED, M]
{
    __shared__ float gates[8][8];                    // U00r,U00i,U01r,U01i,U10r,U10i,U11r,U11i
    __shared__ float xt[MG][TPAD];                   // 8.3 KB
    __shared__ __align__(16) float enc[MG][EPAD];    // 8.1 KB

    const int tid = threadIdx.x;
    const int blk = blockIdx.x;
    const int b   = blk >> 4;        // / NMG
    const int mg  = blk & (NMG - 1);
    const int m0  = mg * MG;

    // --- gate matrices ---
    if (tid < 8) {
        const float phi   = w[tid * 3 + 0];
        const float theta = w[tid * 3 + 1];
        const float omega = w[tid * 3 + 2];
        const float c  = cosf(0.5f * theta), s  = sinf(0.5f * theta);
        const float hf = 0.5f * (phi + omega), df = 0.5f * (phi - omega);
        const float ch = cosf(hf), sh = sinf(hf);
        const float cd = cosf(df), sd = sinf(df);
        gates[tid][0] =  ch * c;  gates[tid][1] = -sh * c;   // U00 = e^{-i hf} c
        gates[tid][2] = -cd * s;  gates[tid][3] = -sd * s;   // U01 = -e^{+i df} s
        gates[tid][4] =  cd * s;  gates[tid][5] = -sd * s;   // U10 = e^{-i df} s
        gates[tid][6] =  ch * c;  gates[tid][7] =  sh * c;   // U11 = e^{+i hf} c
    }

    // --- coalesced staging: x[b, t, m0+c] -> xt[c][t] (one float4 per row) ---
    {
        const float* xb = x + (size_t)b * SEQLEN * NFEAT + m0;
        #pragma unroll
        for (int r = 0; r < 2; ++r) {
            const int t = tid + r * 256;             // 0..511
            const float4 v = *reinterpret_cast<const float4*>(xb + (size_t)t * NFEAT);
            xt[0][t] = v.x;
            xt[1][t] = v.y;
            xt[2][t] = v.z;
            xt[3][t] = v.w;
        }
    }
    __syncthreads();

    // --- phase 1: quantum encoder sims ---
    #pragma unroll 1
    for (int s = tid; s < MG * NPATCH; s += 256) {
        const int m = s & (MG - 1);
        const int p = s >> 2;

        float re[16], im[16];
        float ss = 0.f;
        #pragma unroll
        for (int j = 0; j < PATCHLEN; ++j) {
            const float v = xt[m][p * STRIDE_ + j] + 1e-6f;
            re[j] = v;
            im[j] = 0.f;
            ss += v * v;
        }
        const float inv = rsqrtf(ss);
        #pragma unroll
        for (int j = 0; j < PATCHLEN; ++j) re[j] *= inv;

        #pragma unroll
        for (int l = 0; l < 2; ++l) {
            #pragma unroll
            for (int q = 0; q < 4; ++q) {
                const int g = l * 4 + q;
                const float u00r = gates[g][0], u00i = gates[g][1];
                const float u01r = gates[g][2], u01i = gates[g][3];
                const float u10r = gates[g][4], u10i = gates[g][5];
                const float u11r = gates[g][6], u11i = gates[g][7];
                const int bit = 8 >> q;
                #pragma unroll
                for (int k = 0; k < 16; ++k) {
                    if (k & bit) continue;
                    const int k1 = k | bit;
                    const float a0r = re[k],  a0i = im[k];
                    const float a1r = re[k1], a1i = im[k1];
                    re[k]  = u00r * a0r - u00i * a0i + u01r * a1r - u01i * a1i;
                    im[k]  = u00r * a0i + u00i * a0r + u01r * a1i + u01i * a1r;
                    re[k1] = u10r * a0r - u10i * a0i + u11r * a1r - u11i * a1i;
                    im[k1] = u10r * a0i + u10i * a0r + u11r * a1i + u11i * a1r;
                }
            }
            const int r = (l % 3) + 1;
            #pragma unroll
            for (int i = 0; i < 4; ++i) {
                const int cb = 8 >> i;
                const int tb = 8 >> ((i + r) & 3);
                #pragma unroll
                for (int k = 0; k < 16; ++k) {
                    if ((k & cb) && !(k & tb)) {
                        const int k1 = k | tb;
                        float t;
                        t = re[k]; re[k] = re[k1]; re[k1] = t;
                        t = im[k]; im[k] = im[k1]; im[k1] = t;
                    }
                }
            }
        }

        // probabilities once, then <Z_q> = 1 - 2 * sum_{k & bit} p_k
        float pk[16];
        #pragma unroll
        for (int k = 0; k < 16; ++k) pk[k] = re[k] * re[k] + im[k] * im[k];
        float z[4];
        #pragma unroll
        for (int q = 0; q < 4; ++q) {
            const int bit = 8 >> q;
            float sq = 0.f;
            #pragma unroll
            for (int k = 0; k < 16; ++k) {
                if (k & bit) sq += pk[k];
            }
            z[q] = fmaf(-2.f, sq, 1.f);
        }
        *reinterpret_cast<float4*>(&enc[m][4 * p]) = make_float4(z[0], z[1], z[2], z[3]);
    }
    __syncthreads();

    // --- phase 2: head GEMM: out[b, o, m0+m] = enc[m] . hw[o] + hb[o] ---
    {
        const int m = tid & (MG - 1);
        const float4* e4 = reinterpret_cast<const float4*>(&enc[m][0]);
        #pragma unroll 1
        for (int o = (tid >> 2); o < PREDLEN; o += 64) {
            float acc = hb[o];
            const float4* h4 = reinterpret_cast<const float4*>(hw + (size_t)o * NCOLS);
            #pragma unroll 5
            for (int k = 0; k < NCOLS / 4; ++k) {
                const float4 ev = e4[k];
                const float4 hv = h4[k];
                acc += ev.x * hv.x + ev.y * hv.y + ev.z * hv.z + ev.w * hv.w;
            }
            out[((size_t)b * PREDLEN + o) * NFEAT + m0 + m] = acc;
        }
    }
}

extern "C" void kernel_launch(void* const* d_in, const int* in_sizes, int n_in,
                              void* d_out, int out_size, void* d_ws, size_t ws_size,
                              hipStream_t stream) {
    const float* x  = (const float*)d_in[0];   // [64, 512, 64]
    const float* w  = (const float*)d_in[1];   // [2, 4, 3]
    const float* hw = (const float*)d_in[2];   // [96, 500]
    const float* hb = (const float*)d_in[3];   // [96]
    float* out = (float*)d_out;                // [64, 96, 64]

    dim3 grid(BATCH * NMG);   // 1024 blocks: (b, m-group of 4)
    dim3 block(256);
    qml_fused_kernel<<<grid, block, 0, stream>>>(x, w, hw, hb, out);
}

// Round 4
// 70.577 us; speedup vs baseline: 2.4126x; 2.4126x over previous
//
#include <hip/hip_runtime.h>
#include <cmath>

// Problem constants
#define BATCH 64
#define SEQLEN 512
#define NFEAT 64
#define NPATCH 125
#define PATCHLEN 16
#define STRIDE_ 4
#define PREDLEN 96
#define NCOLS 500        // NPATCH * 4 qubits
#define NROWS (BATCH * NFEAT)  // 4096

// ---------- kernel A: quantum encoder ----------
// MG=4 m's per block -> 1024 blocks x 256 threads (4 blocks/CU exactly).
// Stage x[b,:,m0:m0+4] coalesced-ish (float4/row) into LDS transposed,
// then ~2 sims/thread with state fully in registers; write enc rows to ws.
#define MG 4
#define NMG (NFEAT / MG)   // 16
#define TPAD 521           // odd pad: sim reads spread 2-way over banks (free)

__global__ __launch_bounds__(256) void qml_encoder_kernel(
    const float* __restrict__ x,     // [B, L, M]
    const float* __restrict__ w,     // [2, 4, 3]
    float* __restrict__ enc_ws)      // [NROWS, NCOLS]
{
    __shared__ float gates[8][8];    // U00r,U00i,U01r,U01i,U10r,U10i,U11r,U11i
    __shared__ float xt[MG][TPAD];

    const int tid = threadIdx.x;
    const int blk = blockIdx.x;
    const int b   = blk >> 4;          // / NMG
    const int mg  = blk & (NMG - 1);
    const int m0  = mg * MG;

    // gate matrices (threads 0..7)
    if (tid < 8) {
        const float phi   = w[tid * 3 + 0];
        const float theta = w[tid * 3 + 1];
        const float omega = w[tid * 3 + 2];
        const float c  = cosf(0.5f * theta), s  = sinf(0.5f * theta);
        const float hf = 0.5f * (phi + omega), df = 0.5f * (phi - omega);
        const float ch = cosf(hf), sh = sinf(hf);
        const float cd = cosf(df), sd = sinf(df);
        gates[tid][0] =  ch * c;  gates[tid][1] = -sh * c;   // U00 = e^{-i hf} c
        gates[tid][2] = -cd * s;  gates[tid][3] = -sd * s;   // U01 = -e^{+i df} s
        gates[tid][4] =  cd * s;  gates[tid][5] = -sd * s;   // U10 = e^{-i df} s
        gates[tid][6] =  ch * c;  gates[tid][7] =  sh * c;   // U11 = e^{+i hf} c
    }

    // staging: x[b, t, m0+c] -> xt[c][t]
    {
        const float* xb = x + (size_t)b * SEQLEN * NFEAT + m0;
        #pragma unroll
        for (int r = 0; r < 2; ++r) {
            const int t = tid + r * 256;
            const float4 v = *reinterpret_cast<const float4*>(xb + (size_t)t * NFEAT);
            xt[0][t] = v.x;
            xt[1][t] = v.y;
            xt[2][t] = v.z;
            xt[3][t] = v.w;
        }
    }
    __syncthreads();

    // sims: one statevector per thread, fully unrolled gate ladder
    #pragma unroll 1
    for (int s = tid; s < MG * NPATCH; s += 256) {
        const int m = s & (MG - 1);
        const int p = s >> 2;

        float re[16], im[16];
        float ss = 0.f;
        #pragma unroll
        for (int j = 0; j < PATCHLEN; ++j) {
            const float v = xt[m][p * STRIDE_ + j] + 1e-6f;
            re[j] = v;
            im[j] = 0.f;
            ss += v * v;
        }
        const float inv = rsqrtf(ss);
        #pragma unroll
        for (int j = 0; j < PATCHLEN; ++j) re[j] *= inv;

        #pragma unroll
        for (int l = 0; l < 2; ++l) {
            #pragma unroll
            for (int q = 0; q < 4; ++q) {
                const int g = l * 4 + q;
                const float u00r = gates[g][0], u00i = gates[g][1];
                const float u01r = gates[g][2], u01i = gates[g][3];
                const float u10r = gates[g][4], u10i = gates[g][5];
                const float u11r = gates[g][6], u11i = gates[g][7];
                const int bit = 8 >> q;
                #pragma unroll
                for (int k = 0; k < 16; ++k) {
                    if (k & bit) continue;
                    const int k1 = k | bit;
                    const float a0r = re[k],  a0i = im[k];
                    const float a1r = re[k1], a1i = im[k1];
                    re[k]  = u00r * a0r - u00i * a0i + u01r * a1r - u01i * a1i;
                    im[k]  = u00r * a0i + u00i * a0r + u01r * a1i + u01i * a1r;
                    re[k1] = u10r * a0r - u10i * a0i + u11r * a1r - u11i * a1i;
                    im[k1] = u10r * a0i + u10i * a0r + u11r * a1i + u11i * a1r;
                }
            }
            const int r = (l % 3) + 1;
            #pragma unroll
            for (int i = 0; i < 4; ++i) {
                const int cb = 8 >> i;
                const int tb = 8 >> ((i + r) & 3);
                #pragma unroll
                for (int k = 0; k < 16; ++k) {
                    if ((k & cb) && !(k & tb)) {
                        const int k1 = k | tb;
                        float t;
                        t = re[k]; re[k] = re[k1]; re[k1] = t;
                        t = im[k]; im[k] = im[k1]; im[k1] = t;
                    }
                }
            }
        }

        // <Z_q> = 1 - 2 * sum_{k & bit} p_k (state normalized by unitarity)
        float pk[16];
        #pragma unroll
        for (int k = 0; k < 16; ++k) pk[k] = re[k] * re[k] + im[k] * im[k];
        float z[4];
        #pragma unroll
        for (int q = 0; q < 4; ++q) {
            const int bit = 8 >> q;
            float sq = 0.f;
            #pragma unroll
            for (int k = 0; k < 16; ++k) {
                if (k & bit) sq += pk[k];
            }
            z[q] = fmaf(-2.f, sq, 1.f);
        }
        const size_t row = (size_t)b * NFEAT + m0 + m;
        *reinterpret_cast<float4*>(enc_ws + row * NCOLS + 4 * p) =
            make_float4(z[0], z[1], z[2], z[3]);
    }
}

// ---------- kernel B: head GEMM ----------
// 512 blocks x 256 threads; block handles 8 consecutive rows (same b).
// enc tile [8][500] staged in LDS; thread (r = tid&7, ot = tid>>3) computes
// outs {ot, ot+32, ot+64} for row r: LDS reads are 8-way broadcast, hw reads
// are 8-way broadcast, out writes land in 32B segments.
__global__ __launch_bounds__(256) void qml_head_kernel(
    const float* __restrict__ enc_ws, // [NROWS, NCOLS]
    const float* __restrict__ hw,     // [PRED, NCOLS]
    const float* __restrict__ hb,     // [PRED]
    float* __restrict__ out)          // [B, PRED, M]
{
    __shared__ __align__(16) float et[8 * NCOLS];   // 16 KB

    const int tid = threadIdx.x;
    const int r0  = blockIdx.x * 8;                 // first row of tile

    // stage enc tile (rows are contiguous: 8*500 floats = 1000 float4)
    {
        const float4* src = reinterpret_cast<const float4*>(enc_ws + (size_t)r0 * NCOLS);
        float4* dst = reinterpret_cast<float4*>(et);
        #pragma unroll
        for (int i = 0; i < 4; ++i) {
            const int idx = tid + i * 256;
            if (idx < 1000) dst[idx] = src[idx];
        }
    }
    __syncthreads();

    const int r  = tid & 7;          // row within tile
    const int ot = tid >> 3;         // 0..31
    const int row = r0 + r;
    const int b = row >> 6;
    const int m = row & 63;

    float acc0 = hb[ot];
    float acc1 = hb[ot + 32];
    float acc2 = hb[ot + 64];
    const float4* e4 = reinterpret_cast<const float4*>(et + r * NCOLS);
    const float4* h0 = reinterpret_cast<const float4*>(hw + (size_t)(ot     ) * NCOLS);
    const float4* h1 = reinterpret_cast<const float4*>(hw + (size_t)(ot + 32) * NCOLS);
    const float4* h2 = reinterpret_cast<const float4*>(hw + (size_t)(ot + 64) * NCOLS);
    #pragma unroll 5
    for (int k = 0; k < NCOLS / 4; ++k) {
        const float4 ev = e4[k];
        const float4 a  = h0[k];
        const float4 bb = h1[k];
        const float4 cc = h2[k];
        acc0 += ev.x * a.x  + ev.y * a.y  + ev.z * a.z  + ev.w * a.w;
        acc1 += ev.x * bb.x + ev.y * bb.y + ev.z * bb.z + ev.w * bb.w;
        acc2 += ev.x * cc.x + ev.y * cc.y + ev.z * cc.z + ev.w * cc.w;
    }
    float* ob = out + ((size_t)b * PREDLEN) * NFEAT + m;
    ob[(size_t)(ot     ) * NFEAT] = acc0;
    ob[(size_t)(ot + 32) * NFEAT] = acc1;
    ob[(size_t)(ot + 64) * NFEAT] = acc2;
}

// ---------- fallback: fused single kernel (R2, known-good 55 us) ----------
#define FMG 8
#define FNMG (NFEAT / FMG)
#define FTPAD 521
#define FEPAD 508

__global__ __launch_bounds__(256) void qml_fused_kernel(
    const float* __restrict__ x,
    const float* __restrict__ w,
    const float* __restrict__ hw,
    const float* __restrict__ hb,
    float* __restrict__ out)
{
    __shared__ float gates[8][8];
    __shared__ float xt[FMG][FTPAD];
    __shared__ __align__(16) float enc[FMG][FEPAD];

    const int tid = threadIdx.x;
    const int blk = blockIdx.x;
    const int b   = blk >> 3;
    const int mg  = blk & (FNMG - 1);
    const int m0  = mg * FMG;

    if (tid < 8) {
        const float phi   = w[tid * 3 + 0];
        const float theta = w[tid * 3 + 1];
        const float omega = w[tid * 3 + 2];
        const float c  = cosf(0.5f * theta), s  = sinf(0.5f * theta);
        const float hf = 0.5f * (phi + omega), df = 0.5f * (phi - omega);
        const float ch = cosf(hf), sh = sinf(hf);
        const float cd = cosf(df), sd = sinf(df);
        gates[tid][0] =  ch * c;  gates[tid][1] = -sh * c;
        gates[tid][2] = -cd * s;  gates[tid][3] = -sd * s;
        gates[tid][4] =  cd * s;  gates[tid][5] = -sd * s;
        gates[tid][6] =  ch * c;  gates[tid][7] =  sh * c;
    }
    {
        const float* xb = x + (size_t)b * SEQLEN * NFEAT + m0;
        #pragma unroll
        for (int r = 0; r < 4; ++r) {
            const int idx  = tid + r * 256;
            const int t    = idx >> 1;
            const int half = idx & 1;
            const float4 v = *reinterpret_cast<const float4*>(xb + (size_t)t * NFEAT + 4 * half);
            xt[4 * half + 0][t] = v.x;
            xt[4 * half + 1][t] = v.y;
            xt[4 * half + 2][t] = v.z;
            xt[4 * half + 3][t] = v.w;
        }
    }
    __syncthreads();

    for (int s = tid; s < FMG * NPATCH; s += 256) {
        const int m = s & (FMG - 1);
        const int p = s >> 3;

        float re[16], im[16];
        float ss = 0.f;
        #pragma unroll
        for (int j = 0; j < PATCHLEN; ++j) {
            const float v = xt[m][p * STRIDE_ + j] + 1e-6f;
            re[j] = v;
            im[j] = 0.f;
            ss += v * v;
        }
        const float inv = rsqrtf(ss);
        #pragma unroll
        for (int j = 0; j < PATCHLEN; ++j) re[j] *= inv;

        #pragma unroll
        for (int l = 0; l < 2; ++l) {
            #pragma unroll
            for (int q = 0; q < 4; ++q) {
                const int g = l * 4 + q;
                const float u00r = gates[g][0], u00i = gates[g][1];
                const float u01r = gates[g][2], u01i = gates[g][3];
                const float u10r = gates[g][4], u10i = gates[g][5];
                const float u11r = gates[g][6], u11i = gates[g][7];
                const int bit = 8 >> q;
                #pragma unroll
                for (int k = 0; k < 16; ++k) {
                    if (k & bit) continue;
                    const int k1 = k | bit;
                    const float a0r = re[k],  a0i = im[k];
                    const float a1r = re[k1], a1i = im[k1];
                    re[k]  = u00r * a0r - u00i * a0i + u01r * a1r - u01i * a1i;
                    im[k]  = u00r * a0i + u00i * a0r + u01r * a1i + u01i * a1r;
                    re[k1] = u10r * a0r - u10i * a0i + u11r * a1r - u11i * a1i;
                    im[k1] = u10r * a0i + u10i * a0r + u11r * a1i + u11i * a1r;
                }
            }
            const int r = (l % 3) + 1;
            #pragma unroll
            for (int i = 0; i < 4; ++i) {
                const int cb = 8 >> i;
                const int tb = 8 >> ((i + r) & 3);
                #pragma unroll
                for (int k = 0; k < 16; ++k) {
                    if ((k & cb) && !(k & tb)) {
                        const int k1 = k | tb;
                        float t;
                        t = re[k]; re[k] = re[k1]; re[k1] = t;
                        t = im[k]; im[k] = im[k1]; im[k1] = t;
                    }
                }
            }
        }

        float z[4];
        #pragma unroll
        for (int q = 0; q < 4; ++q) {
            const int bit = 8 >> q;
            float zz = 0.f;
            #pragma unroll
            for (int k = 0; k < 16; ++k) {
                const float pk = re[k] * re[k] + im[k] * im[k];
                zz += (k & bit) ? -pk : pk;
            }
            z[q] = zz;
        }
        *reinterpret_cast<float4*>(&enc[m][4 * p]) = make_float4(z[0], z[1], z[2], z[3]);
    }
    __syncthreads();

    {
        const int m  = tid & (FMG - 1);
        const int o0 = tid >> 3;
        float acc0 = hb[o0];
        float acc1 = hb[o0 + 32];
        float acc2 = hb[o0 + 64];
        const float4* e4 = reinterpret_cast<const float4*>(&enc[m][0]);
        const float4* h0 = reinterpret_cast<const float4*>(hw + (size_t)(o0     ) * NCOLS);
        const float4* h1 = reinterpret_cast<const float4*>(hw + (size_t)(o0 + 32) * NCOLS);
        const float4* h2 = reinterpret_cast<const float4*>(hw + (size_t)(o0 + 64) * NCOLS);
        #pragma unroll 5
        for (int k = 0; k < NCOLS / 4; ++k) {
            const float4 ev = e4[k];
            const float4 a  = h0[k];
            const float4 bb = h1[k];
            const float4 cc = h2[k];
            acc0 += ev.x * a.x  + ev.y * a.y  + ev.z * a.z  + ev.w * a.w;
            acc1 += ev.x * bb.x + ev.y * bb.y + ev.z * bb.z + ev.w * bb.w;
            acc2 += ev.x * cc.x + ev.y * cc.y + ev.z * cc.z + ev.w * cc.w;
        }
        float* ob = out + ((size_t)b * PREDLEN) * NFEAT + m0 + m;
        ob[(size_t)(o0     ) * NFEAT] = acc0;
        ob[(size_t)(o0 + 32) * NFEAT] = acc1;
        ob[(size_t)(o0 + 64) * NFEAT] = acc2;
    }
}

extern "C" void kernel_launch(void* const* d_in, const int* in_sizes, int n_in,
                              void* d_out, int out_size, void* d_ws, size_t ws_size,
                              hipStream_t stream) {
    const float* x  = (const float*)d_in[0];   // [64, 512, 64]
    const float* w  = (const float*)d_in[1];   // [2, 4, 3]
    const float* hw = (const float*)d_in[2];   // [96, 500]
    const float* hb = (const float*)d_in[3];   // [96]
    float* out = (float*)d_out;                // [64, 96, 64]

    const size_t enc_bytes = (size_t)NROWS * NCOLS * sizeof(float);  // 8.192 MB
    if (ws_size >= enc_bytes) {
        float* enc_ws = (float*)d_ws;
        qml_encoder_kernel<<<dim3(BATCH * NMG), dim3(256), 0, stream>>>(x, w, enc_ws);
        qml_head_kernel<<<dim3(NROWS / 8), dim3(256), 0, stream>>>(enc_ws, hw, hb, out);
    } else {
        qml_fused_kernel<<<dim3(BATCH * FNMG), dim3(256), 0, stream>>>(x, w, hw, hb, out);
    }
}

// Round 5
// 58.945 us; speedup vs baseline: 2.8887x; 1.1973x over previous
//
#include <hip/hip_runtime.h>
#include <cmath>

// Problem constants
#define BATCH 64
#define SEQLEN 512
#define NFEAT 64
#define NPATCH 125
#define PATCHLEN 16
#define STRIDE_ 4
#define PREDLEN 96
#define NCOLS 500        // NPATCH * 4 qubits
#define NROWS (BATCH * NFEAT)  // 4096

// ---------- kernel A: quantum encoder ----------
#define MG 4
#define NMG (NFEAT / MG)   // 16
#define TPAD 521           // odd pad: sim reads spread 2-way over banks (free)

__global__ __launch_bounds__(256) void qml_encoder_kernel(
    const float* __restrict__ x,     // [B, L, M]
    const float* __restrict__ w,     // [2, 4, 3]
    float* __restrict__ enc_ws)      // [NROWS, NCOLS]
{
    __shared__ float gates[8][8];    // U00r,U00i,U01r,U01i,U10r,U10i,U11r,U11i
    __shared__ float xt[MG][TPAD];

    const int tid = threadIdx.x;
    const int blk = blockIdx.x;
    const int b   = blk >> 4;          // / NMG
    const int mg  = blk & (NMG - 1);
    const int m0  = mg * MG;

    // gate matrices (threads 0..7)
    if (tid < 8) {
        const float phi   = w[tid * 3 + 0];
        const float theta = w[tid * 3 + 1];
        const float omega = w[tid * 3 + 2];
        const float c  = cosf(0.5f * theta), s  = sinf(0.5f * theta);
        const float hf = 0.5f * (phi + omega), df = 0.5f * (phi - omega);
        const float ch = cosf(hf), sh = sinf(hf);
        const float cd = cosf(df), sd = sinf(df);
        gates[tid][0] =  ch * c;  gates[tid][1] = -sh * c;   // U00 = e^{-i hf} c
        gates[tid][2] = -cd * s;  gates[tid][3] = -sd * s;   // U01 = -e^{+i df} s
        gates[tid][4] =  cd * s;  gates[tid][5] = -sd * s;   // U10 = e^{-i df} s
        gates[tid][6] =  ch * c;  gates[tid][7] =  sh * c;   // U11 = e^{+i hf} c
    }

    // staging: x[b, t, m0+c] -> xt[c][t]
    {
        const float* xb = x + (size_t)b * SEQLEN * NFEAT + m0;
        #pragma unroll
        for (int r = 0; r < 2; ++r) {
            const int t = tid + r * 256;
            const float4 v = *reinterpret_cast<const float4*>(xb + (size_t)t * NFEAT);
            xt[0][t] = v.x;
            xt[1][t] = v.y;
            xt[2][t] = v.z;
            xt[3][t] = v.w;
        }
    }
    __syncthreads();

    // sims: one statevector per thread, fully unrolled gate ladder
    #pragma unroll 1
    for (int s = tid; s < MG * NPATCH; s += 256) {
        const int m = s & (MG - 1);
        const int p = s >> 2;

        float re[16], im[16];
        float ss = 0.f;
        #pragma unroll
        for (int j = 0; j < PATCHLEN; ++j) {
            const float v = xt[m][p * STRIDE_ + j] + 1e-6f;
            re[j] = v;
            im[j] = 0.f;
            ss += v * v;
        }
        const float inv = rsqrtf(ss);
        #pragma unroll
        for (int j = 0; j < PATCHLEN; ++j) re[j] *= inv;

        #pragma unroll
        for (int l = 0; l < 2; ++l) {
            #pragma unroll
            for (int q = 0; q < 4; ++q) {
                const int g = l * 4 + q;
                const float u00r = gates[g][0], u00i = gates[g][1];
                const float u01r = gates[g][2], u01i = gates[g][3];
                const float u10r = gates[g][4], u10i = gates[g][5];
                const float u11r = gates[g][6], u11i = gates[g][7];
                const int bit = 8 >> q;
                #pragma unroll
                for (int k = 0; k < 16; ++k) {
                    if (k & bit) continue;
                    const int k1 = k | bit;
                    const float a0r = re[k],  a0i = im[k];
                    const float a1r = re[k1], a1i = im[k1];
                    re[k]  = u00r * a0r - u00i * a0i + u01r * a1r - u01i * a1i;
                    im[k]  = u00r * a0i + u00i * a0r + u01r * a1i + u01i * a1r;
                    re[k1] = u10r * a0r - u10i * a0i + u11r * a1r - u11i * a1i;
                    im[k1] = u10r * a0i + u10i * a0r + u11r * a1i + u11i * a1r;
                }
            }
            const int r = (l % 3) + 1;
            #pragma unroll
            for (int i = 0; i < 4; ++i) {
                const int cb = 8 >> i;
                const int tb = 8 >> ((i + r) & 3);
                #pragma unroll
                for (int k = 0; k < 16; ++k) {
                    if ((k & cb) && !(k & tb)) {
                        const int k1 = k | tb;
                        float t;
                        t = re[k]; re[k] = re[k1]; re[k1] = t;
                        t = im[k]; im[k] = im[k1]; im[k1] = t;
                    }
                }
            }
        }

        // <Z_q> = 1 - 2 * sum_{k & bit} p_k (state normalized by unitarity)
        float pk[16];
        #pragma unroll
        for (int k = 0; k < 16; ++k) pk[k] = re[k] * re[k] + im[k] * im[k];
        float z[4];
        #pragma unroll
        for (int q = 0; q < 4; ++q) {
            const int bit = 8 >> q;
            float sq = 0.f;
            #pragma unroll
            for (int k = 0; k < 16; ++k) {
                if (k & bit) sq += pk[k];
            }
            z[q] = fmaf(-2.f, sq, 1.f);
        }
        const size_t row = (size_t)b * NFEAT + m0 + m;
        *reinterpret_cast<float4*>(enc_ws + row * NCOLS + 4 * p) =
            make_float4(z[0], z[1], z[2], z[3]);
    }
}

// ---------- kernel B: head GEMM (v2: N-split for occupancy) ----------
// grid (512, 3) x 256 threads. Block (rg, og): 8 rows [8*rg, 8*rg+8),
// 32 cols [32*og, 32*og+32). Thread (r = tid&7, oc = tid>>3) computes ONE
// output over K=500 with 4 partial accumulators (ILP). enc tile in LDS:
// row stride 500 words -> 8 rows land on disjoint bank quads (conflict-free).
__global__ __launch_bounds__(256) void qml_head_kernel(
    const float* __restrict__ enc_ws, // [NROWS, NCOLS]
    const float* __restrict__ hw,     // [PRED, NCOLS]
    const float* __restrict__ hb,     // [PRED]
    float* __restrict__ out)          // [B, PRED, M]
{
    __shared__ __align__(16) float et[8 * NCOLS];   // 16 KB

    const int tid = threadIdx.x;
    const int r0  = blockIdx.x * 8;                 // first row of tile
    const int og  = blockIdx.y;                     // 0..2

    // stage enc tile (8*500 floats = 1000 float4)
    {
        const float4* src = reinterpret_cast<const float4*>(enc_ws + (size_t)r0 * NCOLS);
        float4* dst = reinterpret_cast<float4*>(et);
        #pragma unroll
        for (int i = 0; i < 4; ++i) {
            const int idx = tid + i * 256;
            if (idx < 1000) dst[idx] = src[idx];
        }
    }
    __syncthreads();

    const int r   = tid & 7;          // row within tile
    const int oc  = tid >> 3;         // 0..31
    const int o   = og * 32 + oc;
    const int row = r0 + r;
    const int b   = row >> 6;
    const int m   = row & 63;

    const float4* e4 = reinterpret_cast<const float4*>(et + r * NCOLS);
    const float4* h4 = reinterpret_cast<const float4*>(hw + (size_t)o * NCOLS);

    float a0 = 0.f, a1 = 0.f, a2 = 0.f, a3 = 0.f;
    #pragma unroll 1
    for (int k = 0; k < 124; k += 4) {
        const float4 e0 = e4[k],     h0 = h4[k];
        const float4 e1 = e4[k + 1], h1 = h4[k + 1];
        const float4 e2 = e4[k + 2], h2 = h4[k + 2];
        const float4 e3 = e4[k + 3], h3 = h4[k + 3];
        a0 += e0.x * h0.x + e0.y * h0.y + e0.z * h0.z + e0.w * h0.w;
        a1 += e1.x * h1.x + e1.y * h1.y + e1.z * h1.z + e1.w * h1.w;
        a2 += e2.x * h2.x + e2.y * h2.y + e2.z * h2.z + e2.w * h2.w;
        a3 += e3.x * h3.x + e3.y * h3.y + e3.z * h3.z + e3.w * h3.w;
    }
    {   // tail k = 124
        const float4 e0 = e4[124], h0 = h4[124];
        a0 += e0.x * h0.x + e0.y * h0.y + e0.z * h0.z + e0.w * h0.w;
    }
    const float acc = ((a0 + a1) + (a2 + a3)) + hb[o];
    out[((size_t)b * PREDLEN + o) * NFEAT + m] = acc;
}

// ---------- fallback: fused single kernel (R2, known-good 55 us) ----------
#define FMG 8
#define FNMG (NFEAT / FMG)
#define FTPAD 521
#define FEPAD 508

__global__ __launch_bounds__(256) void qml_fused_kernel(
    const float* __restrict__ x,
    const float* __restrict__ w,
    const float* __restrict__ hw,
    const float* __restrict__ hb,
    float* __restrict__ out)
{
    __shared__ float gates[8][8];
    __shared__ float xt[FMG][FTPAD];
    __shared__ __align__(16) float enc[FMG][FEPAD];

    const int tid = threadIdx.x;
    const int blk = blockIdx.x;
    const int b   = blk >> 3;
    const int mg  = blk & (FNMG - 1);
    const int m0  = mg * FMG;

    if (tid < 8) {
        const float phi   = w[tid * 3 + 0];
        const float theta = w[tid * 3 + 1];
        const float omega = w[tid * 3 + 2];
        const float c  = cosf(0.5f * theta), s  = sinf(0.5f * theta);
        const float hf = 0.5f * (phi + omega), df = 0.5f * (phi - omega);
        const float ch = cosf(hf), sh = sinf(hf);
        const float cd = cosf(df), sd = sinf(df);
        gates[tid][0] =  ch * c;  gates[tid][1] = -sh * c;
        gates[tid][2] = -cd * s;  gates[tid][3] = -sd * s;
        gates[tid][4] =  cd * s;  gates[tid][5] = -sd * s;
        gates[tid][6] =  ch * c;  gates[tid][7] =  sh * c;
    }
    {
        const float* xb = x + (size_t)b * SEQLEN * NFEAT + m0;
        #pragma unroll
        for (int r = 0; r < 4; ++r) {
            const int idx  = tid + r * 256;
            const int t    = idx >> 1;
            const int half = idx & 1;
            const float4 v = *reinterpret_cast<const float4*>(xb + (size_t)t * NFEAT + 4 * half);
            xt[4 * half + 0][t] = v.x;
            xt[4 * half + 1][t] = v.y;
            xt[4 * half + 2][t] = v.z;
            xt[4 * half + 3][t] = v.w;
        }
    }
    __syncthreads();

    for (int s = tid; s < FMG * NPATCH; s += 256) {
        const int m = s & (FMG - 1);
        const int p = s >> 3;

        float re[16], im[16];
        float ss = 0.f;
        #pragma unroll
        for (int j = 0; j < PATCHLEN; ++j) {
            const float v = xt[m][p * STRIDE_ + j] + 1e-6f;
            re[j] = v;
            im[j] = 0.f;
            ss += v * v;
        }
        const float inv = rsqrtf(ss);
        #pragma unroll
        for (int j = 0; j < PATCHLEN; ++j) re[j] *= inv;

        #pragma unroll
        for (int l = 0; l < 2; ++l) {
            #pragma unroll
            for (int q = 0; q < 4; ++q) {
                const int g = l * 4 + q;
                const float u00r = gates[g][0], u00i = gates[g][1];
                const float u01r = gates[g][2], u01i = gates[g][3];
                const float u10r = gates[g][4], u10i = gates[g][5];
                const float u11r = gates[g][6], u11i = gates[g][7];
                const int bit = 8 >> q;
                #pragma unroll
                for (int k = 0; k < 16; ++k) {
                    if (k & bit) continue;
                    const int k1 = k | bit;
                    const float a0r = re[k],  a0i = im[k];
                    const float a1r = re[k1], a1i = im[k1];
                    re[k]  = u00r * a0r - u00i * a0i + u01r * a1r - u01i * a1i;
                    im[k]  = u00r * a0i + u00i * a0r + u01r * a1i + u01i * a1r;
                    re[k1] = u10r * a0r - u10i * a0i + u11r * a1r - u11i * a1i;
                    im[k1] = u10r * a0i + u10i * a0r + u11r * a1i + u11i * a1r;
                }
            }
            const int r = (l % 3) + 1;
            #pragma unroll
            for (int i = 0; i < 4; ++i) {
                const int cb = 8 >> i;
                const int tb = 8 >> ((i + r) & 3);
                #pragma unroll
                for (int k = 0; k < 16; ++k) {
                    if ((k & cb) && !(k & tb)) {
                        const int k1 = k | tb;
                        float t;
                        t = re[k]; re[k] = re[k1]; re[k1] = t;
                        t = im[k]; im[k] = im[k1]; im[k1] = t;
                    }
                }
            }
        }

        float z[4];
        #pragma unroll
        for (int q = 0; q < 4; ++q) {
            const int bit = 8 >> q;
            float zz = 0.f;
            #pragma unroll
            for (int k = 0; k < 16; ++k) {
                const float pk = re[k] * re[k] + im[k] * im[k];
                zz += (k & bit) ? -pk : pk;
            }
            z[q] = zz;
        }
        *reinterpret_cast<float4*>(&enc[m][4 * p]) = make_float4(z[0], z[1], z[2], z[3]);
    }
    __syncthreads();

    {
        const int m  = tid & (FMG - 1);
        const int o0 = tid >> 3;
        float acc0 = hb[o0];
        float acc1 = hb[o0 + 32];
        float acc2 = hb[o0 + 64];
        const float4* e4 = reinterpret_cast<const float4*>(&enc[m][0]);
        const float4* h0 = reinterpret_cast<const float4*>(hw + (size_t)(o0     ) * NCOLS);
        const float4* h1 = reinterpret_cast<const float4*>(hw + (size_t)(o0 + 32) * NCOLS);
        const float4* h2 = reinterpret_cast<const float4*>(hw + (size_t)(o0 + 64) * NCOLS);
        #pragma unroll 5
        for (int k = 0; k < NCOLS / 4; ++k) {
            const float4 ev = e4[k];
            const float4 a  = h0[k];
            const float4 bb = h1[k];
            const float4 cc = h2[k];
            acc0 += ev.x * a.x  + ev.y * a.y  + ev.z * a.z  + ev.w * a.w;
            acc1 += ev.x * bb.x + ev.y * bb.y + ev.z * bb.z + ev.w * bb.w;
            acc2 += ev.x * cc.x + ev.y * cc.y + ev.z * cc.z + ev.w * cc.w;
        }
        float* ob = out + ((size_t)b * PREDLEN) * NFEAT + m0 + m;
        ob[(size_t)(o0     ) * NFEAT] = acc0;
        ob[(size_t)(o0 + 32) * NFEAT] = acc1;
        ob[(size_t)(o0 + 64) * NFEAT] = acc2;
    }
}

extern "C" void kernel_launch(void* const* d_in, const int* in_sizes, int n_in,
                              void* d_out, int out_size, void* d_ws, size_t ws_size,
                              hipStream_t stream) {
    const float* x  = (const float*)d_in[0];   // [64, 512, 64]
    const float* w  = (const float*)d_in[1];   // [2, 4, 3]
    const float* hw = (const float*)d_in[2];   // [96, 500]
    const float* hb = (const float*)d_in[3];   // [96]
    float* out = (float*)d_out;                // [64, 96, 64]

    const size_t enc_bytes = (size_t)NROWS * NCOLS * sizeof(float);  // 8.192 MB
    if (ws_size >= enc_bytes) {
        float* enc_ws = (float*)d_ws;
        qml_encoder_kernel<<<dim3(BATCH * NMG), dim3(256), 0, stream>>>(x, w, enc_ws);
        qml_head_kernel<<<dim3(NROWS / 8, 3), dim3(256), 0, stream>>>(enc_ws, hw, hb, out);
    } else {
        qml_fused_kernel<<<dim3(BATCH * FNMG), dim3(256), 0, stream>>>(x, w, hw, hb, out);
    }
}

// Round 6
// 45.007 us; speedup vs baseline: 3.7833x; 1.3097x over previous
//
#include <hip/hip_runtime.h>
#include <cmath>

// Problem constants
#define BATCH 64
#define SEQLEN 512
#define NFEAT 64
#define NPATCH 125
#define PATCHLEN 16
#define STRIDE_ 4
#define PREDLEN 96
#define NCOLS 500              // NPATCH * 4 qubits
#define KPAD 512               // K padded to 512 for MFMA (zeros in 500..511)
#define NROWS (BATCH * NFEAT)  // 4096

typedef __attribute__((ext_vector_type(8))) short short8;     // 8 bf16 (4 VGPR)
typedef __attribute__((ext_vector_type(4))) float f32x4;      // MFMA acc
typedef __attribute__((ext_vector_type(4))) unsigned short ushort4v;

// f32 -> bf16 RNE, header-independent
__device__ __forceinline__ unsigned short f2bf(float f) {
    unsigned int u = __float_as_uint(f);
    u += 0x7FFFu + ((u >> 16) & 1u);
    return (unsigned short)(u >> 16);
}

// ---------- kernel A: quantum encoder (writes bf16 enc) + hw->bf16 prep ----------
#define MG 4
#define NMG (NFEAT / MG)   // 16
#define TPAD 521           // odd pad: sim reads spread <=2-way over banks (free)

__global__ __launch_bounds__(256) void qml_encoder_kernel(
    const float* __restrict__ x,      // [B, L, M]
    const float* __restrict__ w,      // [2, 4, 3]
    const float* __restrict__ hw,     // [PRED, NCOLS] f32
    unsigned short* __restrict__ encb,// [NROWS][KPAD] bf16
    unsigned short* __restrict__ hwb) // [PRED][KPAD] bf16
{
    const int tid = threadIdx.x;
    const int blk = blockIdx.x;

    // ---- tail blocks: convert head_w to bf16 with K-pad zeros ----
    if (blk >= BATCH * NMG) {
        const int bi = blk - BATCH * NMG;        // 0..23
        const int o  = bi * 4 + (tid >> 6);      // 0..95
        const int k8 = (tid & 63) * 8;           // 0..504
        short8 sv;
        #pragma unroll
        for (int j = 0; j < 8; ++j) {
            const int k = k8 + j;
            sv[j] = (k < NCOLS) ? (short)f2bf(hw[(size_t)o * NCOLS + k]) : (short)0;
        }
        *reinterpret_cast<short8*>(hwb + (size_t)o * KPAD + k8) = sv;
        return;
    }

    __shared__ float gates[8][8];    // U00r,U00i,U01r,U01i,U10r,U10i,U11r,U11i
    __shared__ float xt[MG][TPAD];

    const int b   = blk >> 4;          // / NMG
    const int mg  = blk & (NMG - 1);
    const int m0  = mg * MG;

    // gate matrices (threads 0..7)
    if (tid < 8) {
        const float phi   = w[tid * 3 + 0];
        const float theta = w[tid * 3 + 1];
        const float omega = w[tid * 3 + 2];
        const float c  = cosf(0.5f * theta), s  = sinf(0.5f * theta);
        const float hf = 0.5f * (phi + omega), df = 0.5f * (phi - omega);
        const float ch = cosf(hf), sh = sinf(hf);
        const float cd = cosf(df), sd = sinf(df);
        gates[tid][0] =  ch * c;  gates[tid][1] = -sh * c;   // U00 = e^{-i hf} c
        gates[tid][2] = -cd * s;  gates[tid][3] = -sd * s;   // U01 = -e^{+i df} s
        gates[tid][4] =  cd * s;  gates[tid][5] = -sd * s;   // U10 = e^{-i df} s
        gates[tid][6] =  ch * c;  gates[tid][7] =  sh * c;   // U11 = e^{+i hf} c
    }

    // K-pad zeros for this block's 4 enc rows (k = 500..511)
    if (tid < MG) {
        unsigned short* dst = encb + ((size_t)b * NFEAT + m0 + tid) * KPAD + NCOLS;
        #pragma unroll
        for (int j = 0; j < KPAD - NCOLS; ++j) dst[j] = 0;
    }

    // staging: x[b, t, m0+c] -> xt[c][t]
    {
        const float* xb = x + (size_t)b * SEQLEN * NFEAT + m0;
        #pragma unroll
        for (int r = 0; r < 2; ++r) {
            const int t = tid + r * 256;
            const float4 v = *reinterpret_cast<const float4*>(xb + (size_t)t * NFEAT);
            xt[0][t] = v.x;
            xt[1][t] = v.y;
            xt[2][t] = v.z;
            xt[3][t] = v.w;
        }
    }
    __syncthreads();

    // sims: one statevector per thread, fully unrolled gate ladder
    #pragma unroll 1
    for (int s = tid; s < MG * NPATCH; s += 256) {
        const int m = s & (MG - 1);
        const int p = s >> 2;

        float re[16], im[16];
        float ss = 0.f;
        #pragma unroll
        for (int j = 0; j < PATCHLEN; ++j) {
            const float v = xt[m][p * STRIDE_ + j] + 1e-6f;
            re[j] = v;
            im[j] = 0.f;
            ss += v * v;
        }
        const float inv = rsqrtf(ss);
        #pragma unroll
        for (int j = 0; j < PATCHLEN; ++j) re[j] *= inv;

        #pragma unroll
        for (int l = 0; l < 2; ++l) {
            #pragma unroll
            for (int q = 0; q < 4; ++q) {
                const int g = l * 4 + q;
                const float u00r = gates[g][0], u00i = gates[g][1];
                const float u01r = gates[g][2], u01i = gates[g][3];
                const float u10r = gates[g][4], u10i = gates[g][5];
                const float u11r = gates[g][6], u11i = gates[g][7];
                const int bit = 8 >> q;
                #pragma unroll
                for (int k = 0; k < 16; ++k) {
                    if (k & bit) continue;
                    const int k1 = k | bit;
                    const float a0r = re[k],  a0i = im[k];
                    const float a1r = re[k1], a1i = im[k1];
                    re[k]  = u00r * a0r - u00i * a0i + u01r * a1r - u01i * a1i;
                    im[k]  = u00r * a0i + u00i * a0r + u01r * a1i + u01i * a1r;
                    re[k1] = u10r * a0r - u10i * a0i + u11r * a1r - u11i * a1i;
                    im[k1] = u10r * a0i + u10i * a0r + u11r * a1i + u11i * a1r;
                }
            }
            const int r = (l % 3) + 1;
            #pragma unroll
            for (int i = 0; i < 4; ++i) {
                const int cb = 8 >> i;
                const int tb = 8 >> ((i + r) & 3);
                #pragma unroll
                for (int k = 0; k < 16; ++k) {
                    if ((k & cb) && !(k & tb)) {
                        const int k1 = k | tb;
                        float t;
                        t = re[k]; re[k] = re[k1]; re[k1] = t;
                        t = im[k]; im[k] = im[k1]; im[k1] = t;
                    }
                }
            }
        }

        // <Z_q> = 1 - 2 * sum_{k & bit} p_k (state normalized by unitarity)
        float pk[16];
        #pragma unroll
        for (int k = 0; k < 16; ++k) pk[k] = re[k] * re[k] + im[k] * im[k];
        float z[4];
        #pragma unroll
        for (int q = 0; q < 4; ++q) {
            const int bit = 8 >> q;
            float sq = 0.f;
            #pragma unroll
            for (int k = 0; k < 16; ++k) {
                if (k & bit) sq += pk[k];
            }
            z[q] = fmaf(-2.f, sq, 1.f);
        }
        const size_t row = (size_t)b * NFEAT + m0 + m;
        ushort4v zv;
        zv[0] = f2bf(z[0]); zv[1] = f2bf(z[1]); zv[2] = f2bf(z[2]); zv[3] = f2bf(z[3]);
        *reinterpret_cast<ushort4v*>(encb + row * KPAD + 4 * p) = zv;
    }
}

// ---------- kernel B: head GEMM via bf16 MFMA ----------
// C[4096,96] = E[4096,512]_bf16 . Wt[96,512]_bf16^T, f32 accumulate.
// 384 blocks x 256 threads (4 waves). Wave = one 16x16 output tile:
// block covers 64 rows x 16 cols; grid = 64 rowgroups x 6 colgroups.
// Fragment mapping (m89-verified): A lane l <- E[row0+(l&15)][kc+8*(l>>4)];
// B lane l <- Wt[col0+(l&15)][kc+8*(l>>4)]; D: col=l&15, row=4*(l>>4)+reg.
__global__ __launch_bounds__(256) void qml_head_mfma(
    const unsigned short* __restrict__ encb, // [NROWS][KPAD] bf16
    const unsigned short* __restrict__ hwb,  // [PRED][KPAD] bf16
    const float* __restrict__ hb,            // [PRED]
    float* __restrict__ out)                 // [B, PRED, M]
{
    const int tid  = threadIdx.x;
    const int l    = tid & 63;
    const int wv   = tid >> 6;                 // wave 0..3
    const int rg   = blockIdx.x & 63;          // row-group (4 tiles)
    const int ct   = blockIdx.x >> 6;          // col-tile 0..5
    const int row0 = (rg * 4 + wv) * 16;
    const int col0 = ct * 16;

    const int lr = l & 15;                     // A-row / B-col within tile
    const int kg = l >> 4;                     // k-group 0..3

    const short* ea = (const short*)encb + (size_t)(row0 + lr) * KPAD + kg * 8;
    const short* wb = (const short*)hwb  + (size_t)(col0 + lr) * KPAD + kg * 8;

    f32x4 acc = {0.f, 0.f, 0.f, 0.f};
    #pragma unroll
    for (int kc = 0; kc < KPAD / 32; ++kc) {   // 16 chunks of K=32
        const short8 a = *reinterpret_cast<const short8*>(ea + kc * 32);
        const short8 bfr = *reinterpret_cast<const short8*>(wb + kc * 32);
        acc = __builtin_amdgcn_mfma_f32_16x16x32_bf16(a, bfr, acc, 0, 0, 0);
    }

    const int o    = col0 + lr;                // lane's column (same for all 4 regs)
    const float bias = hb[o];
    #pragma unroll
    for (int j = 0; j < 4; ++j) {
        const int r = row0 + kg * 4 + j;       // global enc row
        const int b = r >> 6;
        const int m = r & 63;
        out[((size_t)b * PREDLEN + o) * NFEAT + m] = acc[j] + bias;
    }
}

// ---------- fallback: fused single kernel (R2, known-good 55 us) ----------
#define FMG 8
#define FNMG (NFEAT / FMG)
#define FTPAD 521
#define FEPAD 508

__global__ __launch_bounds__(256) void qml_fused_kernel(
    const float* __restrict__ x,
    const float* __restrict__ w,
    const float* __restrict__ hw,
    const float* __restrict__ hb,
    float* __restrict__ out)
{
    __shared__ float gates[8][8];
    __shared__ float xt[FMG][FTPAD];
    __shared__ __align__(16) float enc[FMG][FEPAD];

    const int tid = threadIdx.x;
    const int blk = blockIdx.x;
    const int b   = blk >> 3;
    const int mg  = blk & (FNMG - 1);
    const int m0  = mg * FMG;

    if (tid < 8) {
        const float phi   = w[tid * 3 + 0];
        const float theta = w[tid * 3 + 1];
        const float omega = w[tid * 3 + 2];
        const float c  = cosf(0.5f * theta), s  = sinf(0.5f * theta);
        const float hf = 0.5f * (phi + omega), df = 0.5f * (phi - omega);
        const float ch = cosf(hf), sh = sinf(hf);
        const float cd = cosf(df), sd = sinf(df);
        gates[tid][0] =  ch * c;  gates[tid][1] = -sh * c;
        gates[tid][2] = -cd * s;  gates[tid][3] = -sd * s;
        gates[tid][4] =  cd * s;  gates[tid][5] = -sd * s;
        gates[tid][6] =  ch * c;  gates[tid][7] =  sh * c;
    }
    {
        const float* xb = x + (size_t)b * SEQLEN * NFEAT + m0;
        #pragma unroll
        for (int r = 0; r < 4; ++r) {
            const int idx  = tid + r * 256;
            const int t    = idx >> 1;
            const int half = idx & 1;
            const float4 v = *reinterpret_cast<const float4*>(xb + (size_t)t * NFEAT + 4 * half);
            xt[4 * half + 0][t] = v.x;
            xt[4 * half + 1][t] = v.y;
            xt[4 * half + 2][t] = v.z;
            xt[4 * half + 3][t] = v.w;
        }
    }
    __syncthreads();

    for (int s = tid; s < FMG * NPATCH; s += 256) {
        const int m = s & (FMG - 1);
        const int p = s >> 3;

        float re[16], im[16];
        float ss = 0.f;
        #pragma unroll
        for (int j = 0; j < PATCHLEN; ++j) {
            const float v = xt[m][p * STRIDE_ + j] + 1e-6f;
            re[j] = v;
            im[j] = 0.f;
            ss += v * v;
        }
        const float inv = rsqrtf(ss);
        #pragma unroll
        for (int j = 0; j < PATCHLEN; ++j) re[j] *= inv;

        #pragma unroll
        for (int l = 0; l < 2; ++l) {
            #pragma unroll
            for (int q = 0; q < 4; ++q) {
                const int g = l * 4 + q;
                const float u00r = gates[g][0], u00i = gates[g][1];
                const float u01r = gates[g][2], u01i = gates[g][3];
                const float u10r = gates[g][4], u10i = gates[g][5];
                const float u11r = gates[g][6], u11i = gates[g][7];
                const int bit = 8 >> q;
                #pragma unroll
                for (int k = 0; k < 16; ++k) {
                    if (k & bit) continue;
                    const int k1 = k | bit;
                    const float a0r = re[k],  a0i = im[k];
                    const float a1r = re[k1], a1i = im[k1];
                    re[k]  = u00r * a0r - u00i * a0i + u01r * a1r - u01i * a1i;
                    im[k]  = u00r * a0i + u00i * a0r + u01r * a1i + u01i * a1r;
                    re[k1] = u10r * a0r - u10i * a0i + u11r * a1r - u11i * a1i;
                    im[k1] = u10r * a0i + u10i * a0r + u11r * a1i + u11i * a1r;
                }
            }
            const int r = (l % 3) + 1;
            #pragma unroll
            for (int i = 0; i < 4; ++i) {
                const int cb = 8 >> i;
                const int tb = 8 >> ((i + r) & 3);
                #pragma unroll
                for (int k = 0; k < 16; ++k) {
                    if ((k & cb) && !(k & tb)) {
                        const int k1 = k | tb;
                        float t;
                        t = re[k]; re[k] = re[k1]; re[k1] = t;
                        t = im[k]; im[k] = im[k1]; im[k1] = t;
                    }
                }
            }
        }

        float z[4];
        #pragma unroll
        for (int q = 0; q < 4; ++q) {
            const int bit = 8 >> q;
            float zz = 0.f;
            #pragma unroll
            for (int k = 0; k < 16; ++k) {
                const float pk = re[k] * re[k] + im[k] * im[k];
                zz += (k & bit) ? -pk : pk;
            }
            z[q] = zz;
        }
        *reinterpret_cast<float4*>(&enc[m][4 * p]) = make_float4(z[0], z[1], z[2], z[3]);
    }
    __syncthreads();

    {
        const int m  = tid & (FMG - 1);
        const int o0 = tid >> 3;
        float acc0 = hb[o0];
        float acc1 = hb[o0 + 32];
        float acc2 = hb[o0 + 64];
        const float4* e4 = reinterpret_cast<const float4*>(&enc[m][0]);
        const float4* h0 = reinterpret_cast<const float4*>(hw + (size_t)(o0     ) * NCOLS);
        const float4* h1 = reinterpret_cast<const float4*>(hw + (size_t)(o0 + 32) * NCOLS);
        const float4* h2 = reinterpret_cast<const float4*>(hw + (size_t)(o0 + 64) * NCOLS);
        #pragma unroll 5
        for (int k = 0; k < NCOLS / 4; ++k) {
            const float4 ev = e4[k];
            const float4 a  = h0[k];
            const float4 bb = h1[k];
            const float4 cc = h2[k];
            acc0 += ev.x * a.x  + ev.y * a.y  + ev.z * a.z  + ev.w * a.w;
            acc1 += ev.x * bb.x + ev.y * bb.y + ev.z * bb.z + ev.w * bb.w;
            acc2 += ev.x * cc.x + ev.y * cc.y + ev.z * cc.z + ev.w * cc.w;
        }
        float* ob = out + ((size_t)b * PREDLEN) * NFEAT + m0 + m;
        ob[(size_t)(o0     ) * NFEAT] = acc0;
        ob[(size_t)(o0 + 32) * NFEAT] = acc1;
        ob[(size_t)(o0 + 64) * NFEAT] = acc2;
    }
}

extern "C" void kernel_launch(void* const* d_in, const int* in_sizes, int n_in,
                              void* d_out, int out_size, void* d_ws, size_t ws_size,
                              hipStream_t stream) {
    const float* x  = (const float*)d_in[0];   // [64, 512, 64]
    const float* w  = (const float*)d_in[1];   // [2, 4, 3]
    const float* hw = (const float*)d_in[2];   // [96, 500]
    const float* hb = (const float*)d_in[3];   // [96]
    float* out = (float*)d_out;                // [64, 96, 64]

    const size_t enc_bytes = (size_t)NROWS * KPAD * sizeof(unsigned short);  // 4 MB
    const size_t hwb_bytes = (size_t)PREDLEN * KPAD * sizeof(unsigned short);
    if (ws_size >= enc_bytes + hwb_bytes) {
        unsigned short* encb = (unsigned short*)d_ws;
        unsigned short* hwb  = encb + (size_t)NROWS * KPAD;
        qml_encoder_kernel<<<dim3(BATCH * NMG + 24), dim3(256), 0, stream>>>(x, w, hw, encb, hwb);
        qml_head_mfma<<<dim3(64 * 6), dim3(256), 0, stream>>>(encb, hwb, hb, out);
    } else {
        qml_fused_kernel<<<dim3(BATCH * FNMG), dim3(256), 0, stream>>>(x, w, hw, hb, out);
    }
}

// Round 7
// 37.806 us; speedup vs baseline: 4.5040x; 1.1905x over previous
//
#include <hip/hip_runtime.h>
#include <cmath>

// Problem constants
#define BATCH 64
#define SEQLEN 512
#define NFEAT 64
#define NPATCH 125
#define PATCHLEN 16
#define STRIDE_ 4
#define PREDLEN 96
#define NCOLS 500              // NPATCH * 4 qubits
#define KPAD 512               // K padded to 512 for head MFMA
#define NROWS (BATCH * NFEAT)  // 4096

typedef __attribute__((ext_vector_type(8))) short short8;   // 8 bf16 (4 VGPR)
typedef __attribute__((ext_vector_type(4))) float f32x4;    // MFMA acc

// f32 -> bf16 RNE
__device__ __forceinline__ unsigned short f2bf(float f) {
    unsigned int u = __float_as_uint(f);
    u += 0x7FFFu + ((u >> 16) & 1u);
    return (unsigned short)(u >> 16);
}
__device__ __forceinline__ float bf2f(unsigned short h) {
    return __uint_as_float(((unsigned int)h) << 16);
}

// ---- shared gate-ladder pieces (verified in R1-R6 kernels) ----
__device__ __forceinline__ void build_gate(const float* __restrict__ w, int g,
                                           float gates[8][8]) {
    const float phi   = w[g * 3 + 0];
    const float theta = w[g * 3 + 1];
    const float omega = w[g * 3 + 2];
    const float c  = cosf(0.5f * theta), s  = sinf(0.5f * theta);
    const float hf = 0.5f * (phi + omega), df = 0.5f * (phi - omega);
    const float ch = cosf(hf), sh = sinf(hf);
    const float cd = cosf(df), sd = sinf(df);
    gates[g][0] =  ch * c;  gates[g][1] = -sh * c;   // U00 = e^{-i hf} c
    gates[g][2] = -cd * s;  gates[g][3] = -sd * s;   // U01 = -e^{+i df} s
    gates[g][4] =  cd * s;  gates[g][5] = -sd * s;   // U10 = e^{-i df} s
    gates[g][6] =  ch * c;  gates[g][7] =  sh * c;   // U11 = e^{+i hf} c
}

__device__ __forceinline__ void run_ladder(float re[16], float im[16],
                                           const float gates[8][8]) {
    #pragma unroll
    for (int l = 0; l < 2; ++l) {
        #pragma unroll
        for (int q = 0; q < 4; ++q) {
            const int g = l * 4 + q;
            const float u00r = gates[g][0], u00i = gates[g][1];
            const float u01r = gates[g][2], u01i = gates[g][3];
            const float u10r = gates[g][4], u10i = gates[g][5];
            const float u11r = gates[g][6], u11i = gates[g][7];
            const int bit = 8 >> q;
            #pragma unroll
            for (int k = 0; k < 16; ++k) {
                if (k & bit) continue;
                const int k1 = k | bit;
                const float a0r = re[k],  a0i = im[k];
                const float a1r = re[k1], a1i = im[k1];
                re[k]  = u00r * a0r - u00i * a0i + u01r * a1r - u01i * a1i;
                im[k]  = u00r * a0i + u00i * a0r + u01r * a1i + u01i * a1r;
                re[k1] = u10r * a0r - u10i * a0i + u11r * a1r - u11i * a1i;
                im[k1] = u10r * a0i + u10i * a0r + u11r * a1i + u11i * a1r;
            }
        }
        const int r = (l % 3) + 1;
        #pragma unroll
        for (int i = 0; i < 4; ++i) {
            const int cb = 8 >> i;
            const int tb = 8 >> ((i + r) & 3);
            #pragma unroll
            for (int k = 0; k < 16; ++k) {
                if ((k & cb) && !(k & tb)) {
                    const int k1 = k | tb;
                    float t;
                    t = re[k]; re[k] = re[k1]; re[k1] = t;
                    t = im[k]; im[k] = im[k1]; im[k1] = t;
                }
            }
        }
    }
}

// ---------- kernel A: prep — extract U via basis states; convert head_w ----------
// block 0: threads 0..7 build gates; threads 0..15 push basis vector e_j
// through the circuit -> column j of U; G[32][16] = [Re U; Im U] (f32, ws).
// blocks 1..24: head_w -> bf16 [96][KPAD] (K-pad zeros).
__global__ __launch_bounds__(256) void qml_prep_kernel(
    const float* __restrict__ w,        // [2,4,3]
    const float* __restrict__ hw,       // [PRED, NCOLS]
    float* __restrict__ G,              // [32][16]
    unsigned short* __restrict__ hwb)   // [PRED][KPAD]
{
    const int tid = threadIdx.x;
    if (blockIdx.x == 0) {
        __shared__ float gates[8][8];
        if (tid < 8) build_gate(w, tid, gates);
        __syncthreads();
        if (tid < 16) {
            float re[16], im[16];
            #pragma unroll
            for (int k = 0; k < 16; ++k) { re[k] = (k == tid) ? 1.f : 0.f; im[k] = 0.f; }
            run_ladder(re, im, gates);
            #pragma unroll
            for (int k = 0; k < 16; ++k) {
                G[k * 16 + tid]        = re[k];   // rows 0..15  = Re U
                G[(16 + k) * 16 + tid] = im[k];   // rows 16..31 = Im U
            }
        }
    } else {
        const int bi = blockIdx.x - 1;           // 0..23
        const int o  = bi * 4 + (tid >> 6);      // 0..95
        const int k8 = (tid & 63) * 8;           // 0..504
        short8 sv;
        #pragma unroll
        for (int j = 0; j < 8; ++j) {
            const int k = k8 + j;
            sv[j] = (k < NCOLS) ? (short)f2bf(hw[(size_t)o * NCOLS + k]) : (short)0;
        }
        *reinterpret_cast<short8*>(hwb + (size_t)o * KPAD + k8) = sv;
    }
}

// ---------- kernel B: encoder via MFMA Born rule ----------
// T = G.v per patch; p_k = T_k^2 + T_{16+k}^2; z_q = 1 - 2*sum_mask p / sum_all p.
// Grid 1024 (b x m-group of 4) x 256. Per m: T[32][128] as 2 M-tiles x 8 N-tiles
// of 16x16x32 MFMA; hi/lo bf16 split on BOTH operands:
//   A1=[Gh|Gh], A2=[Gl|Gl], B=[Vh;Vl]  =>  A1.B + A2.B = G.(Vh+Vl) ~= G.V (f32-acc)
// Fragment maps (m89-verified, same as head): A lane(lr,kg)<-A[lr][kg*8..+7];
// B lane <- (B^T)[p0+lr][kg*8..+7]; D: col=lr(=patch), row=4*kg+reg(=k-row).
#define MG 4
#define XT_LD 544   // 512 + 32 zero-pad words (tail patches read zeros)

__global__ __launch_bounds__(256) void qml_enc_mfma(
    const float* __restrict__ x,        // [B, L, M]
    const float* __restrict__ G,        // [32][16] f32
    unsigned short* __restrict__ encb)  // [NROWS][KPAD] bf16
{
    __shared__ float xt[MG][XT_LD];     // 8.7 KB

    const int tid  = threadIdx.x;
    const int lane = tid & 63;
    const int lr   = lane & 15;
    const int kg   = lane >> 4;
    const int wv   = tid >> 6;          // wave 0..3
    const int b    = blockIdx.x >> 4;
    const int m0   = (blockIdx.x & 15) * MG;

    // stage x[b, :, m0..m0+3] -> xt[c][t]; zero tail words
    {
        const float* xb = x + (size_t)b * SEQLEN * NFEAT + m0;
        for (int t = tid; t < XT_LD; t += 256) {
            float4 v = (t < SEQLEN) ? *reinterpret_cast<const float4*>(xb + (size_t)t * NFEAT)
                                    : make_float4(0.f, 0.f, 0.f, 0.f);
            xt[0][t] = v.x; xt[1][t] = v.y; xt[2][t] = v.z; xt[3][t] = v.w;
        }
    }

    // A-fragments (constant per kernel): lane reads G[mt*16+lr][(kg&1)*8 + c]
    short8 ah0, al0, ah1, al1;
    {
        const int koff = (kg & 1) * 8;
        #pragma unroll
        for (int c = 0; c < 8; ++c) {
            const float g0 = G[(lr) * 16 + koff + c];
            unsigned short h0 = f2bf(g0);
            ah0[c] = (short)h0;
            al0[c] = (short)f2bf(g0 - bf2f(h0));
            const float g1 = G[(16 + lr) * 16 + koff + c];
            unsigned short h1 = f2bf(g1);
            ah1[c] = (short)h1;
            al1[c] = (short)f2bf(g1 - bf2f(h1));
        }
    }
    __syncthreads();

    const size_t rowbase = (size_t)b * NFEAT + m0;
    #pragma unroll 1
    for (int m = 0; m < MG; ++m) {
        const float4* row4 = reinterpret_cast<const float4*>(&xt[m][0]);
        #pragma unroll
        for (int i = 0; i < 2; ++i) {
            const int nt = wv * 2 + i;     // N-tile 0..7
            const int p  = nt * 16 + lr;   // patch 0..127

            // B-fragment: 8 f32 from xt (j-range (kg&1)*8), +1e-6, hi/lo split
            const int u = p + 2 * (kg & 1);     // float4 unit index
            const float4 xv0 = row4[u];
            const float4 xv1 = row4[u + 1];
            const float vv[8] = {xv0.x, xv0.y, xv0.z, xv0.w,
                                 xv1.x, xv1.y, xv1.z, xv1.w};
            short8 bfrag;
            #pragma unroll
            for (int c = 0; c < 8; ++c) {
                const float v = vv[c] + 1e-6f;
                const unsigned short h  = f2bf(v);
                const unsigned short lo = f2bf(v - bf2f(h));
                bfrag[c] = (kg < 2) ? (short)h : (short)lo;
            }

            f32x4 zz = {0.f, 0.f, 0.f, 0.f};
            f32x4 acc0 = __builtin_amdgcn_mfma_f32_16x16x32_bf16(
                al0, bfrag, zz, 0, 0, 0);
            acc0 = __builtin_amdgcn_mfma_f32_16x16x32_bf16(ah0, bfrag, acc0, 0, 0, 0);
            f32x4 acc1 = __builtin_amdgcn_mfma_f32_16x16x32_bf16(
                al1, bfrag, zz, 0, 0, 0);
            acc1 = __builtin_amdgcn_mfma_f32_16x16x32_bf16(ah1, bfrag, acc1, 0, 0, 0);

            // probs for this lane's 4 k-rows (k = 4*kg + j)
            const float p0 = acc0[0] * acc0[0] + acc1[0] * acc1[0];
            const float p1 = acc0[1] * acc0[1] + acc1[1] * acc1[1];
            const float p2 = acc0[2] * acc0[2] + acc1[2] * acc1[2];
            const float p3 = acc0[3] * acc0[3] + acc1[3] * acc1[3];
            const float psum = (p0 + p1) + (p2 + p3);
            // masked sums: q0 <-> k&8 = kg&2; q1 <-> k&4 = kg&1; q2 <-> j&2; q3 <-> j&1
            float s0 = (kg & 2) ? psum : 0.f;
            float s1 = (kg & 1) ? psum : 0.f;
            float s2 = p2 + p3;
            float s3 = p1 + p3;
            float sa = psum;
            // butterfly over the 4 k-groups (lanes lr, lr+16, lr+32, lr+48)
            s0 += __shfl_xor(s0, 16); s0 += __shfl_xor(s0, 32);
            s1 += __shfl_xor(s1, 16); s1 += __shfl_xor(s1, 32);
            s2 += __shfl_xor(s2, 16); s2 += __shfl_xor(s2, 32);
            s3 += __shfl_xor(s3, 16); s3 += __shfl_xor(s3, 32);
            sa += __shfl_xor(sa, 16); sa += __shfl_xor(sa, 32);

            const float rinv = 1.f / sa;                 // sa = |v|^2 > 0
            const float ssel = (kg == 0) ? s0 : (kg == 1) ? s1 : (kg == 2) ? s2 : s3;
            const float zval = 1.f - 2.f * ssel * rinv;  // z_{q=kg}
            const unsigned short outv = (p < NPATCH) ? f2bf(zval) : (unsigned short)0;
            encb[(rowbase + m) * KPAD + 4 * p + kg] = outv;   // cols [4p0,4p0+64) contiguous
        }
    }
}

// ---------- kernel C: head GEMM via bf16 MFMA (verified in R6) ----------
__global__ __launch_bounds__(256) void qml_head_mfma(
    const unsigned short* __restrict__ encb, // [NROWS][KPAD] bf16
    const unsigned short* __restrict__ hwb,  // [PRED][KPAD] bf16
    const float* __restrict__ hb,            // [PRED]
    float* __restrict__ out)                 // [B, PRED, M]
{
    const int tid  = threadIdx.x;
    const int l    = tid & 63;
    const int wv   = tid >> 6;                 // wave 0..3
    const int rg   = blockIdx.x & 63;          // row-group (4 tiles)
    const int ct   = blockIdx.x >> 6;          // col-tile 0..5
    const int row0 = (rg * 4 + wv) * 16;
    const int col0 = ct * 16;

    const int lr = l & 15;
    const int kg = l >> 4;

    const short* ea = (const short*)encb + (size_t)(row0 + lr) * KPAD + kg * 8;
    const short* wb = (const short*)hwb  + (size_t)(col0 + lr) * KPAD + kg * 8;

    f32x4 acc = {0.f, 0.f, 0.f, 0.f};
    #pragma unroll
    for (int kc = 0; kc < KPAD / 32; ++kc) {
        const short8 a   = *reinterpret_cast<const short8*>(ea + kc * 32);
        const short8 bfr = *reinterpret_cast<const short8*>(wb + kc * 32);
        acc = __builtin_amdgcn_mfma_f32_16x16x32_bf16(a, bfr, acc, 0, 0, 0);
    }

    const int o = col0 + lr;
    const float bias = hb[o];
    #pragma unroll
    for (int j = 0; j < 4; ++j) {
        const int r = row0 + kg * 4 + j;
        const int b = r >> 6;
        const int m = r & 63;
        out[((size_t)b * PREDLEN + o) * NFEAT + m] = acc[j] + bias;
    }
}

// ---------- fallback: fused single kernel (R2-style, known-good) ----------
#define FMG 8
#define FNMG (NFEAT / FMG)
#define FTPAD 521
#define FEPAD 508

__global__ __launch_bounds__(256) void qml_fused_kernel(
    const float* __restrict__ x,
    const float* __restrict__ w,
    const float* __restrict__ hw,
    const float* __restrict__ hb,
    float* __restrict__ out)
{
    __shared__ float gates[8][8];
    __shared__ float xt[FMG][FTPAD];
    __shared__ __align__(16) float enc[FMG][FEPAD];

    const int tid = threadIdx.x;
    const int blk = blockIdx.x;
    const int b   = blk >> 3;
    const int mg  = blk & (FNMG - 1);
    const int m0  = mg * FMG;

    if (tid < 8) build_gate(w, tid, gates);
    {
        const float* xb = x + (size_t)b * SEQLEN * NFEAT + m0;
        #pragma unroll
        for (int r = 0; r < 4; ++r) {
            const int idx  = tid + r * 256;
            const int t    = idx >> 1;
            const int half = idx & 1;
            const float4 v = *reinterpret_cast<const float4*>(xb + (size_t)t * NFEAT + 4 * half);
            xt[4 * half + 0][t] = v.x;
            xt[4 * half + 1][t] = v.y;
            xt[4 * half + 2][t] = v.z;
            xt[4 * half + 3][t] = v.w;
        }
    }
    __syncthreads();

    for (int s = tid; s < FMG * NPATCH; s += 256) {
        const int m = s & (FMG - 1);
        const int p = s >> 3;

        float re[16], im[16];
        float ss = 0.f;
        #pragma unroll
        for (int j = 0; j < PATCHLEN; ++j) {
            const float v = xt[m][p * STRIDE_ + j] + 1e-6f;
            re[j] = v; im[j] = 0.f; ss += v * v;
        }
        const float inv = rsqrtf(ss);
        #pragma unroll
        for (int j = 0; j < PATCHLEN; ++j) re[j] *= inv;

        run_ladder(re, im, gates);

        float pk[16];
        #pragma unroll
        for (int k = 0; k < 16; ++k) pk[k] = re[k] * re[k] + im[k] * im[k];
        float z[4];
        #pragma unroll
        for (int q = 0; q < 4; ++q) {
            const int bit = 8 >> q;
            float sq = 0.f;
            #pragma unroll
            for (int k = 0; k < 16; ++k) if (k & bit) sq += pk[k];
            z[q] = fmaf(-2.f, sq, 1.f);
        }
        *reinterpret_cast<float4*>(&enc[m][4 * p]) = make_float4(z[0], z[1], z[2], z[3]);
    }
    __syncthreads();

    {
        const int m  = tid & (FMG - 1);
        const int o0 = tid >> 3;
        float acc0 = hb[o0];
        float acc1 = hb[o0 + 32];
        float acc2 = hb[o0 + 64];
        const float4* e4 = reinterpret_cast<const float4*>(&enc[m][0]);
        const float4* h0 = reinterpret_cast<const float4*>(hw + (size_t)(o0     ) * NCOLS);
        const float4* h1 = reinterpret_cast<const float4*>(hw + (size_t)(o0 + 32) * NCOLS);
        const float4* h2 = reinterpret_cast<const float4*>(hw + (size_t)(o0 + 64) * NCOLS);
        #pragma unroll 5
        for (int k = 0; k < NCOLS / 4; ++k) {
            const float4 ev = e4[k];
            const float4 a  = h0[k];
            const float4 bb = h1[k];
            const float4 cc = h2[k];
            acc0 += ev.x * a.x  + ev.y * a.y  + ev.z * a.z  + ev.w * a.w;
            acc1 += ev.x * bb.x + ev.y * bb.y + ev.z * bb.z + ev.w * bb.w;
            acc2 += ev.x * cc.x + ev.y * cc.y + ev.z * cc.z + ev.w * cc.w;
        }
        float* ob = out + ((size_t)b * PREDLEN) * NFEAT + m0 + m;
        ob[(size_t)(o0     ) * NFEAT] = acc0;
        ob[(size_t)(o0 + 32) * NFEAT] = acc1;
        ob[(size_t)(o0 + 64) * NFEAT] = acc2;
    }
}

extern "C" void kernel_launch(void* const* d_in, const int* in_sizes, int n_in,
                              void* d_out, int out_size, void* d_ws, size_t ws_size,
                              hipStream_t stream) {
    const float* x  = (const float*)d_in[0];   // [64, 512, 64]
    const float* w  = (const float*)d_in[1];   // [2, 4, 3]
    const float* hw = (const float*)d_in[2];   // [96, 500]
    const float* hb = (const float*)d_in[3];   // [96]
    float* out = (float*)d_out;                // [64, 96, 64]

    const size_t encb_bytes = (size_t)NROWS * KPAD * sizeof(unsigned short); // 4 MB
    const size_t hwb_bytes  = (size_t)PREDLEN * KPAD * sizeof(unsigned short);
    const size_t g_bytes    = 32 * 16 * sizeof(float);
    if (ws_size >= encb_bytes + hwb_bytes + g_bytes) {
        unsigned short* encb = (unsigned short*)d_ws;
        unsigned short* hwb  = encb + (size_t)NROWS * KPAD;
        float*          G    = (float*)(hwb + (size_t)PREDLEN * KPAD);
        qml_prep_kernel<<<dim3(25), dim3(256), 0, stream>>>(w, hw, G, hwb);
        qml_enc_mfma<<<dim3(BATCH * (NFEAT / MG)), dim3(256), 0, stream>>>(x, G, encb);
        qml_head_mfma<<<dim3(64 * 6), dim3(256), 0, stream>>>(encb, hwb, hb, out);
    } else {
        qml_fused_kernel<<<dim3(BATCH * FNMG), dim3(256), 0, stream>>>(x, w, hw, hb, out);
    }
}

// Round 8
// 33.532 us; speedup vs baseline: 5.0780x; 1.1275x over previous
//
#include <hip/hip_runtime.h>
#include <cmath>

// Problem constants
#define BATCH 64
#define SEQLEN 512
#define NFEAT 64
#define NPATCH 125
#define PREDLEN 96
#define NCOLS 500
#define KPAD 512

#define MG 16        // m-rows per block
#define XROW 528     // xh/xl row length in ushorts: 512 + 16 zero tail (patches 125..127 read zeros)
#define ELD 520      // enc LDS row stride (ushorts): 512 + 8 pad -> 4-bank row rotation on head reads

typedef __attribute__((ext_vector_type(8))) short short8;   // 8 bf16 (4 VGPR)
typedef __attribute__((ext_vector_type(4))) short short4v;  // 4 bf16 (2 VGPR)
typedef __attribute__((ext_vector_type(4))) float f32x4;    // MFMA acc

__device__ __forceinline__ unsigned short f2bf(float f) {   // f32 -> bf16 RNE
    unsigned int u = __float_as_uint(f);
    u += 0x7FFFu + ((u >> 16) & 1u);
    return (unsigned short)(u >> 16);
}
__device__ __forceinline__ float bf2f(unsigned short h) {
    return __uint_as_float(((unsigned int)h) << 16);
}

// ---- gate ladder (verified R1-R7) ----
__device__ __forceinline__ void build_gate(const float* __restrict__ w, int g,
                                           float gates[8][8]) {
    const float phi   = w[g * 3 + 0];
    const float theta = w[g * 3 + 1];
    const float omega = w[g * 3 + 2];
    const float c  = cosf(0.5f * theta), s  = sinf(0.5f * theta);
    const float hf = 0.5f * (phi + omega), df = 0.5f * (phi - omega);
    const float ch = cosf(hf), sh = sinf(hf);
    const float cd = cosf(df), sd = sinf(df);
    gates[g][0] =  ch * c;  gates[g][1] = -sh * c;   // U00 = e^{-i hf} c
    gates[g][2] = -cd * s;  gates[g][3] = -sd * s;   // U01 = -e^{+i df} s
    gates[g][4] =  cd * s;  gates[g][5] = -sd * s;   // U10 = e^{-i df} s
    gates[g][6] =  ch * c;  gates[g][7] =  sh * c;   // U11 = e^{+i hf} c
}

__device__ __forceinline__ void run_ladder(float re[16], float im[16],
                                           const float gates[8][8]) {
    #pragma unroll
    for (int l = 0; l < 2; ++l) {
        #pragma unroll
        for (int q = 0; q < 4; ++q) {
            const int g = l * 4 + q;
            const float u00r = gates[g][0], u00i = gates[g][1];
            const float u01r = gates[g][2], u01i = gates[g][3];
            const float u10r = gates[g][4], u10i = gates[g][5];
            const float u11r = gates[g][6], u11i = gates[g][7];
            const int bit = 8 >> q;
            #pragma unroll
            for (int k = 0; k < 16; ++k) {
                if (k & bit) continue;
                const int k1 = k | bit;
                const float a0r = re[k],  a0i = im[k];
                const float a1r = re[k1], a1i = im[k1];
                re[k]  = u00r * a0r - u00i * a0i + u01r * a1r - u01i * a1i;
                im[k]  = u00r * a0i + u00i * a0r + u01r * a1i + u01i * a1r;
                re[k1] = u10r * a0r - u10i * a0i + u11r * a1r - u11i * a1i;
                im[k1] = u10r * a0i + u10i * a0r + u11r * a1i + u11i * a1r;
            }
        }
        const int r = (l % 3) + 1;
        #pragma unroll
        for (int i = 0; i < 4; ++i) {
            const int cb = 8 >> i;
            const int tb = 8 >> ((i + r) & 3);
            #pragma unroll
            for (int k = 0; k < 16; ++k) {
                if ((k & cb) && !(k & tb)) {
                    const int k1 = k | tb;
                    float t;
                    t = re[k]; re[k] = re[k1]; re[k1] = t;
                    t = im[k]; im[k] = im[k1]; im[k1] = t;
                }
            }
        }
    }
}

// ---------- the single fused kernel ----------
// grid 256 = (b, quarter) ; 1024 threads = 16 waves ; no workspace.
// phase 0: stage x[b,:,m0:m0+16] -> LDS pre-split bf16 hi/lo; build gates.
// phase 0b: 16 lanes push basis vectors through circuit -> G[32][16] (LDS).
// phase 1 (enc): wave w = row m; 8 N-tiles of 16 patches; per tile 4 MFMAs
//   (hi/lo split: (Gh+Gl)Â·(vh+vl) folded as in R7, verified); z -> enc LDS.
// phase 2 (head): waves 0..5 = col-tiles; E from LDS, W = hw f32 converted
//   on the fly; verified R6 fragment/D mapping.
__global__ __launch_bounds__(1024) void qml_one(
    const float* __restrict__ x,     // [B, L, M]
    const float* __restrict__ w,     // [2, 4, 3]
    const float* __restrict__ hw,    // [PRED, NCOLS] f32
    const float* __restrict__ hb,    // [PRED]
    float* __restrict__ out)         // [B, PRED, M]
{
    __shared__ float gates[8][8];
    __shared__ float G[32 * 16];                    // [ReU; ImU], row k, col j
    __shared__ unsigned short xh[MG][XROW];         // 16.5 KB
    __shared__ unsigned short xl[MG][XROW];         // 16.5 KB
    __shared__ unsigned short enc[MG][ELD];         // 16.3 KB

    const int tid = threadIdx.x;
    const int b   = blockIdx.x >> 2;
    const int q   = blockIdx.x & 3;
    const int m0  = q * MG;

    if (tid < 8) build_gate(w, tid, gates);

    // ---- phase 0: stage + hi/lo split (each x element split exactly once) ----
    {
        const float* xb = x + (size_t)b * SEQLEN * NFEAT + m0;
        for (int idx = tid; idx < XROW * 2; idx += 1024) {
            const int t    = idx >> 1;
            const int half = idx & 1;
            float4 v0, v1;
            if (t < SEQLEN) {
                v0 = *reinterpret_cast<const float4*>(xb + (size_t)t * NFEAT + 8 * half);
                v1 = *reinterpret_cast<const float4*>(xb + (size_t)t * NFEAT + 8 * half + 4);
            } else {
                v0 = make_float4(0.f, 0.f, 0.f, 0.f);
                v1 = v0;
            }
            const float vals[8] = {v0.x, v0.y, v0.z, v0.w, v1.x, v1.y, v1.z, v1.w};
            #pragma unroll
            for (int c = 0; c < 8; ++c) {
                const float v = vals[c] + 1e-6f;
                const unsigned short h = f2bf(v);
                xh[8 * half + c][t] = h;
                xl[8 * half + c][t] = f2bf(v - bf2f(h));
            }
        }
    }
    __syncthreads();

    // ---- phase 0b: extract U columns via basis states ----
    if (tid < 16) {
        float re[16], im[16];
        #pragma unroll
        for (int k = 0; k < 16; ++k) { re[k] = (k == tid) ? 1.f : 0.f; im[k] = 0.f; }
        run_ladder(re, im, gates);
        #pragma unroll
        for (int k = 0; k < 16; ++k) {
            G[k * 16 + tid]        = re[k];   // Re U
            G[(16 + k) * 16 + tid] = im[k];   // Im U
        }
    }
    __syncthreads();

    const int lane = tid & 63;
    const int lr   = lane & 15;
    const int kg   = lane >> 4;
    const int wv   = tid >> 6;          // wave 0..15

    // ---- A-fragments from G (constant per thread; R7-verified folding) ----
    short8 ah0, al0, ah1, al1;
    {
        const int koff = (kg & 1) * 8;
        #pragma unroll
        for (int c = 0; c < 8; ++c) {
            const float g0 = G[lr * 16 + koff + c];
            const unsigned short h0 = f2bf(g0);
            ah0[c] = (short)h0;
            al0[c] = (short)f2bf(g0 - bf2f(h0));
            const float g1 = G[(16 + lr) * 16 + koff + c];
            const unsigned short h1 = f2bf(g1);
            ah1[c] = (short)h1;
            al1[c] = (short)f2bf(g1 - bf2f(h1));
        }
    }

    // ---- phase 1: encoder; wave wv owns row m = wv ----
    {
        const int m = wv;
        const unsigned short* xrow = (kg < 2) ? &xh[m][0] : &xl[m][0];
        #pragma unroll 1
        for (int nt = 0; nt < 8; ++nt) {
            const int p = nt * 16 + lr;   // patch 0..127

            // B-fragment: 8 consecutive pre-split bf16 (two b64 LDS reads)
            const short4v* src = reinterpret_cast<const short4v*>(xrow + 4 * p + (kg & 1) * 8);
            const short4v s0 = src[0];
            const short4v s1 = src[1];
            short8 bfrag;
            #pragma unroll
            for (int c = 0; c < 4; ++c) { bfrag[c] = s0[c]; bfrag[c + 4] = s1[c]; }

            const f32x4 zz = {0.f, 0.f, 0.f, 0.f};
            f32x4 acc0 = __builtin_amdgcn_mfma_f32_16x16x32_bf16(al0, bfrag, zz, 0, 0, 0);
            acc0 = __builtin_amdgcn_mfma_f32_16x16x32_bf16(ah0, bfrag, acc0, 0, 0, 0);
            f32x4 acc1 = __builtin_amdgcn_mfma_f32_16x16x32_bf16(al1, bfrag, zz, 0, 0, 0);
            acc1 = __builtin_amdgcn_mfma_f32_16x16x32_bf16(ah1, bfrag, acc1, 0, 0, 0);

            // probs for this lane's 4 k-rows (k = 4*kg + j)
            const float p0 = acc0[0] * acc0[0] + acc1[0] * acc1[0];
            const float p1 = acc0[1] * acc0[1] + acc1[1] * acc1[1];
            const float p2 = acc0[2] * acc0[2] + acc1[2] * acc1[2];
            const float p3 = acc0[3] * acc0[3] + acc1[3] * acc1[3];
            const float psum = (p0 + p1) + (p2 + p3);
            // masked sums: q0 <-> k&8 = kg&2; q1 <-> k&4 = kg&1; q2 <-> j&2; q3 <-> j&1
            float s0v = (kg & 2) ? psum : 0.f;
            float s1v = (kg & 1) ? psum : 0.f;
            float s2v = p2 + p3;
            float s3v = p1 + p3;
            float sav = psum;
            s0v += __shfl_xor(s0v, 16); s0v += __shfl_xor(s0v, 32);
            s1v += __shfl_xor(s1v, 16); s1v += __shfl_xor(s1v, 32);
            s2v += __shfl_xor(s2v, 16); s2v += __shfl_xor(s2v, 32);
            s3v += __shfl_xor(s3v, 16); s3v += __shfl_xor(s3v, 32);
            sav += __shfl_xor(sav, 16); sav += __shfl_xor(sav, 32);

            const float rinv = 1.f / sav;               // sav = |v|^2 > 0
            const float ssel = (kg == 0) ? s0v : (kg == 1) ? s1v : (kg == 2) ? s2v : s3v;
            const float zval = 1.f - 2.f * ssel * rinv; // z_{q=kg} for patch p
            enc[m][4 * p + kg] = (p < NPATCH) ? f2bf(zval) : (unsigned short)0;
        }
    }
    __syncthreads();

    // ---- phase 2: head GEMM; waves 0..5 = 16-col tiles ----
    if (wv < 6) {
        const int o = wv * 16 + lr;                 // output column (A/B lr both index 16-tiles)
        const float* hwrow = hw + (size_t)o * NCOLS;
        const unsigned short* erow = &enc[lr][0];

        f32x4 acc = {0.f, 0.f, 0.f, 0.f};
        #pragma unroll 2
        for (int kc = 0; kc < 15; ++kc) {
            const int k0 = kc * 32 + kg * 8;
            const short8 e = *reinterpret_cast<const short8*>(erow + k0);
            const float4 w0 = *reinterpret_cast<const float4*>(hwrow + k0);
            const float4 w1 = *reinterpret_cast<const float4*>(hwrow + k0 + 4);
            short8 wf;
            wf[0] = (short)f2bf(w0.x); wf[1] = (short)f2bf(w0.y);
            wf[2] = (short)f2bf(w0.z); wf[3] = (short)f2bf(w0.w);
            wf[4] = (short)f2bf(w1.x); wf[5] = (short)f2bf(w1.y);
            wf[6] = (short)f2bf(w1.z); wf[7] = (short)f2bf(w1.w);
            acc = __builtin_amdgcn_mfma_f32_16x16x32_bf16(e, wf, acc, 0, 0, 0);
        }
        {   // kc = 15 peel: k in [480, 512); zero-pad k >= 500
            const int k0 = 480 + kg * 8;
            const short8 e = *reinterpret_cast<const short8*>(erow + k0);
            short8 wf;
            #pragma unroll
            for (int c = 0; c < 8; ++c) {
                const int k = k0 + c;
                wf[c] = (k < NCOLS) ? (short)f2bf(hwrow[k]) : (short)0;
            }
            acc = __builtin_amdgcn_mfma_f32_16x16x32_bf16(e, wf, acc, 0, 0, 0);
        }

        const float bias = hb[o];
        #pragma unroll
        for (int j = 0; j < 4; ++j) {
            const int m = m0 + 4 * kg + j;          // D row = 4*kg + j -> enc row
            out[((size_t)b * PREDLEN + o) * NFEAT + m] = acc[j] + bias;
        }
    }
}

extern "C" void kernel_launch(void* const* d_in, const int* in_sizes, int n_in,
                              void* d_out, int out_size, void* d_ws, size_t ws_size,
                              hipStream_t stream) {
    const float* x  = (const float*)d_in[0];   // [64, 512, 64]
    const float* w  = (const float*)d_in[1];   // [2, 4, 3]
    const float* hw = (const float*)d_in[2];   // [96, 500]
    const float* hb = (const float*)d_in[3];   // [96]
    float* out = (float*)d_out;                // [64, 96, 64]

    (void)d_ws; (void)ws_size; (void)in_sizes; (void)n_in; (void)out_size;
    qml_one<<<dim3(BATCH * 4), dim3(1024), 0, stream>>>(x, w, hw, hb, out);
}

// Round 9
// 28.412 us; speedup vs baseline: 5.9931x; 1.1802x over previous
//
#include <hip/hip_runtime.h>
#include <cmath>

// Problem constants
#define BATCH 64
#define SEQLEN 512
#define NFEAT 64
#define NPATCH 125
#define PREDLEN 96
#define NCOLS 500

#define MG 8         // m-rows per block
#define XROW 528     // xh/xl row length (ushorts): 512 + 16 zero tail (patches 125..127)
#define ELD 520      // enc LDS row stride (ushorts)

typedef __attribute__((ext_vector_type(8))) short short8;   // 8 bf16 (4 VGPR)
typedef __attribute__((ext_vector_type(4))) short short4v;  // 4 bf16 (2 VGPR)
typedef __attribute__((ext_vector_type(4))) float f32x4;    // MFMA acc

__device__ __forceinline__ unsigned short f2bf(float f) {   // f32 -> bf16 RNE
    unsigned int u = __float_as_uint(f);
    u += 0x7FFFu + ((u >> 16) & 1u);
    return (unsigned short)(u >> 16);
}
__device__ __forceinline__ float bf2f(unsigned short h) {
    return __uint_as_float(((unsigned int)h) << 16);
}

// ---------- single fused kernel ----------
// grid 512 = (b, 8-m-group); 512 threads = 8 waves; 2 blocks/CU; no workspace.
// phase 0 (parallel): wave 0 builds circuit matrix G=[ReU;ImU] (gates in regs,
//   shfl-broadcast, basis-vector ladder -> LDS); waves 1..7 stage
//   x[b,:,m0:m0+8] -> LDS pre-split bf16 hi/lo.
// phase 1 (enc, all 8 waves): wave w = row m; 8 N-tiles x 4 MFMA (hi/lo
//   split, R7/R8-verified); z -> enc LDS (bf16).
// phase 2 (head, waves 0..5): 16-col tile each; A rows 8..15 duplicate
//   (lr&7) and their D rows are discarded (kg<2 stores only).
__global__ __launch_bounds__(512) void qml_one(
    const float* __restrict__ x,     // [B, L, M]
    const float* __restrict__ w,     // [2, 4, 3]
    const float* __restrict__ hw,    // [PRED, NCOLS] f32
    const float* __restrict__ hb,    // [PRED]
    float* __restrict__ out)         // [B, PRED, M]
{
    __shared__ float G[32 * 16];                    // [ReU; ImU], row k, col j
    __shared__ unsigned short xh[MG][XROW];         // 8.25 KB
    __shared__ unsigned short xl[MG][XROW];         // 8.25 KB
    __shared__ unsigned short enc[MG][ELD];         // 8.1 KB

    const int tid  = threadIdx.x;
    const int lane = tid & 63;
    const int lr   = lane & 15;
    const int kg   = lane >> 4;
    const int wv   = tid >> 6;          // wave 0..7
    const int b    = blockIdx.x >> 3;
    const int m0   = (blockIdx.x & 7) * MG;

    if (wv == 0) {
        // ---- wave 0: gates in registers, shfl broadcast, basis ladder ----
        float my[8];
        {
            const int  g     = lane & 7;
            const float phi   = w[g * 3 + 0];
            const float theta = w[g * 3 + 1];
            const float omega = w[g * 3 + 2];
            const float c  = cosf(0.5f * theta), s  = sinf(0.5f * theta);
            const float hf = 0.5f * (phi + omega), df = 0.5f * (phi - omega);
            const float ch = cosf(hf), sh = sinf(hf);
            const float cd = cosf(df), sd = sinf(df);
            my[0] =  ch * c;  my[1] = -sh * c;   // U00 = e^{-i hf} c
            my[2] = -cd * s;  my[3] = -sd * s;   // U01 = -e^{+i df} s
            my[4] =  cd * s;  my[5] = -sd * s;   // U10 = e^{-i df} s
            my[6] =  ch * c;  my[7] =  sh * c;   // U11 = e^{+i hf} c
        }
        float re[16], im[16];
        #pragma unroll
        for (int k = 0; k < 16; ++k) { re[k] = (k == (lane & 15)) ? 1.f : 0.f; im[k] = 0.f; }
        #pragma unroll
        for (int l = 0; l < 2; ++l) {
            #pragma unroll
            for (int qq = 0; qq < 4; ++qq) {
                const int g = l * 4 + qq;
                const float u00r = __shfl(my[0], g), u00i = __shfl(my[1], g);
                const float u01r = __shfl(my[2], g), u01i = __shfl(my[3], g);
                const float u10r = __shfl(my[4], g), u10i = __shfl(my[5], g);
                const float u11r = __shfl(my[6], g), u11i = __shfl(my[7], g);
                const int bit = 8 >> qq;
                #pragma unroll
                for (int k = 0; k < 16; ++k) {
                    if (k & bit) continue;
                    const int k1 = k | bit;
                    const float a0r = re[k],  a0i = im[k];
                    const float a1r = re[k1], a1i = im[k1];
                    re[k]  = u00r * a0r - u00i * a0i + u01r * a1r - u01i * a1i;
                    im[k]  = u00r * a0i + u00i * a0r + u01r * a1i + u01i * a1r;
                    re[k1] = u10r * a0r - u10i * a0i + u11r * a1r - u11i * a1i;
                    im[k1] = u10r * a0i + u10i * a0r + u11r * a1i + u11i * a1r;
                }
            }
            const int r = (l % 3) + 1;
            #pragma unroll
            for (int i = 0; i < 4; ++i) {
                const int cb = 8 >> i;
                const int tb = 8 >> ((i + r) & 3);
                #pragma unroll
                for (int k = 0; k < 16; ++k) {
                    if ((k & cb) && !(k & tb)) {
                        const int k1 = k | tb;
                        float t;
                        t = re[k]; re[k] = re[k1]; re[k1] = t;
                        t = im[k]; im[k] = im[k1]; im[k1] = t;
                    }
                }
            }
        }
        if (lane < 16) {
            #pragma unroll
            for (int k = 0; k < 16; ++k) {
                G[k * 16 + lane]        = re[k];   // Re U
                G[(16 + k) * 16 + lane] = im[k];   // Im U
            }
        }
    } else {
        // ---- waves 1..7: stage x -> LDS, hi/lo split once per element ----
        const float* xb = x + (size_t)b * SEQLEN * NFEAT + m0;
        for (int idx = tid - 64; idx < XROW * 2; idx += 448) {
            const int t    = idx >> 1;
            const int half = idx & 1;
            float4 v = (t < SEQLEN)
                ? *reinterpret_cast<const float4*>(xb + (size_t)t * NFEAT + 4 * half)
                : make_float4(0.f, 0.f, 0.f, 0.f);
            const float vals[4] = {v.x, v.y, v.z, v.w};
            #pragma unroll
            for (int c = 0; c < 4; ++c) {
                const float vv = vals[c] + 1e-6f;
                const unsigned short h = f2bf(vv);
                xh[4 * half + c][t] = h;
                xl[4 * half + c][t] = f2bf(vv - bf2f(h));
            }
        }
    }
    __syncthreads();

    // ---- A-fragments from G (R7-verified folding) ----
    short8 ah0, al0, ah1, al1;
    {
        const int koff = (kg & 1) * 8;
        #pragma unroll
        for (int c = 0; c < 8; ++c) {
            const float g0 = G[lr * 16 + koff + c];
            const unsigned short h0 = f2bf(g0);
            ah0[c] = (short)h0;
            al0[c] = (short)f2bf(g0 - bf2f(h0));
            const float g1 = G[(16 + lr) * 16 + koff + c];
            const unsigned short h1 = f2bf(g1);
            ah1[c] = (short)h1;
            al1[c] = (short)f2bf(g1 - bf2f(h1));
        }
    }

    // ---- phase 1: encoder; wave wv owns row m = wv ----
    {
        const int m = wv;
        const unsigned short* xrow = (kg < 2) ? &xh[m][0] : &xl[m][0];
        #pragma unroll 1
        for (int nt = 0; nt < 8; ++nt) {
            const int p = nt * 16 + lr;   // patch 0..127

            const short4v* src = reinterpret_cast<const short4v*>(xrow + 4 * p + (kg & 1) * 8);
            const short4v s0 = src[0];
            const short4v s1 = src[1];
            short8 bfrag;
            #pragma unroll
            for (int c = 0; c < 4; ++c) { bfrag[c] = s0[c]; bfrag[c + 4] = s1[c]; }

            const f32x4 zz = {0.f, 0.f, 0.f, 0.f};
            f32x4 acc0 = __builtin_amdgcn_mfma_f32_16x16x32_bf16(al0, bfrag, zz, 0, 0, 0);
            acc0 = __builtin_amdgcn_mfma_f32_16x16x32_bf16(ah0, bfrag, acc0, 0, 0, 0);
            f32x4 acc1 = __builtin_amdgcn_mfma_f32_16x16x32_bf16(al1, bfrag, zz, 0, 0, 0);
            acc1 = __builtin_amdgcn_mfma_f32_16x16x32_bf16(ah1, bfrag, acc1, 0, 0, 0);

            // probs for this lane's 4 k-rows (k = 4*kg + j)
            const float p0 = acc0[0] * acc0[0] + acc1[0] * acc1[0];
            const float p1 = acc0[1] * acc0[1] + acc1[1] * acc1[1];
            const float p2 = acc0[2] * acc0[2] + acc1[2] * acc1[2];
            const float p3 = acc0[3] * acc0[3] + acc1[3] * acc1[3];
            const float psum = (p0 + p1) + (p2 + p3);
            // masked sums: q0 <-> k&8 = kg&2; q1 <-> k&4 = kg&1; q2 <-> j&2; q3 <-> j&1
            float s0v = (kg & 2) ? psum : 0.f;
            float s1v = (kg & 1) ? psum : 0.f;
            float s2v = p2 + p3;
            float s3v = p1 + p3;
            float sav = psum;
            s0v += __shfl_xor(s0v, 16); s0v += __shfl_xor(s0v, 32);
            s1v += __shfl_xor(s1v, 16); s1v += __shfl_xor(s1v, 32);
            s2v += __shfl_xor(s2v, 16); s2v += __shfl_xor(s2v, 32);
            s3v += __shfl_xor(s3v, 16); s3v += __shfl_xor(s3v, 32);
            sav += __shfl_xor(sav, 16); sav += __shfl_xor(sav, 32);

            const float rinv = 1.f / sav;               // sav = |v|^2 > 0
            const float ssel = (kg == 0) ? s0v : (kg == 1) ? s1v : (kg == 2) ? s2v : s3v;
            const float zval = 1.f - 2.f * ssel * rinv; // z_{q=kg} for patch p
            enc[m][4 * p + kg] = (p < NPATCH) ? f2bf(zval) : (unsigned short)0;
        }
    }
    __syncthreads();

    // ---- phase 2: head GEMM; waves 0..5 = 16-col tiles ----
    if (wv < 6) {
        const int o = wv * 16 + lr;                 // output column
        const float* hwrow = hw + (size_t)o * NCOLS;
        const unsigned short* erow = &enc[lr & 7][0];   // rows 8..15 duplicated, discarded

        f32x4 acc = {0.f, 0.f, 0.f, 0.f};
        #pragma unroll 2
        for (int kc = 0; kc < 15; ++kc) {
            const int k0 = kc * 32 + kg * 8;
            const short8 e = *reinterpret_cast<const short8*>(erow + k0);
            const float4 w0 = *reinterpret_cast<const float4*>(hwrow + k0);
            const float4 w1 = *reinterpret_cast<const float4*>(hwrow + k0 + 4);
            short8 wf;
            wf[0] = (short)f2bf(w0.x); wf[1] = (short)f2bf(w0.y);
            wf[2] = (short)f2bf(w0.z); wf[3] = (short)f2bf(w0.w);
            wf[4] = (short)f2bf(w1.x); wf[5] = (short)f2bf(w1.y);
            wf[6] = (short)f2bf(w1.z); wf[7] = (short)f2bf(w1.w);
            acc = __builtin_amdgcn_mfma_f32_16x16x32_bf16(e, wf, acc, 0, 0, 0);
        }
        {   // kc = 15 peel: k in [480, 512); zero-pad k >= 500
            const int k0 = 480 + kg * 8;
            const short8 e = *reinterpret_cast<const short8*>(erow + k0);
            short8 wf;
            #pragma unroll
            for (int c = 0; c < 8; ++c) {
                const int k = k0 + c;
                wf[c] = (k < NCOLS) ? (short)f2bf(hwrow[k]) : (short)0;
            }
            acc = __builtin_amdgcn_mfma_f32_16x16x32_bf16(e, wf, acc, 0, 0, 0);
        }

        if (kg < 2) {                               // D rows 0..7 valid (MG=8)
            const float bias = hb[o];
            #pragma unroll
            for (int j = 0; j < 4; ++j) {
                const int m = m0 + 4 * kg + j;
                out[((size_t)b * PREDLEN + o) * NFEAT + m] = acc[j] + bias;
            }
        }
    }
}

extern "C" void kernel_launch(void* const* d_in, const int* in_sizes, int n_in,
                              void* d_out, int out_size, void* d_ws, size_t ws_size,
                              hipStream_t stream) {
    const float* x  = (const float*)d_in[0];   // [64, 512, 64]
    const float* w  = (const float*)d_in[1];   // [2, 4, 3]
    const float* hw = (const float*)d_in[2];   // [96, 500]
    const float* hb = (const float*)d_in[3];   // [96]
    float* out = (float*)d_out;                // [64, 96, 64]

    (void)d_ws; (void)ws_size; (void)in_sizes; (void)n_in; (void)out_size;
    qml_one<<<dim3(BATCH * MG), dim3(512), 0, stream>>>(x, w, hw, hb, out);
}